// Round 1
// baseline (3396.827 us; speedup 1.0000x reference)
//
#include <hip/hip_runtime.h>
#include <math.h>

// STHM layer, fp32 baseline. B=4, TS=64, SEG=128, D=256, H=8, dh=32, DFF=1024.
// M (rows) = 32768 for every big GEMM. Workspace: 5 slots x 8388608 floats + tiny.

__device__ __forceinline__ float gelu_exact(float x) {
    return 0.5f * x * (1.0f + erff(x * 0.70710678118654752f));
}

// ---------------- Tiled fp32 GEMM: C = A(M,K) @ W(K,N) + bias [+R] [gelu] ----
template<int GELU, int RES>
__global__ __launch_bounds__(256)
void gemm64(const float* __restrict__ A, const float* __restrict__ W,
            const float* __restrict__ bias, const float* __restrict__ R,
            float* __restrict__ C, int M, int N, int K)
{
    __shared__ float As[16][68];   // [k][m], padded: 68*4B = 17*16B (aligned float4 rows)
    __shared__ float Bs[16][68];   // [k][n]
    const int t  = threadIdx.x;
    const int bn = blockIdx.x;
    const int bm = blockIdx.y;
    const int tx = t & 15, ty = t >> 4;
    const int ar = t >> 2, ac = (t & 3) << 2;     // A-tile: 64 rows x 16 cols, float4/thread
    const int wr = t >> 4, wc = (t & 15) << 2;    // W-tile: 16 rows x 64 cols, float4/thread
    const float* Ap = A + (size_t)(bm * 64 + ar) * K + ac;
    const float* Wp = W + (size_t)wr * N + (size_t)bn * 64 + wc;
    float acc[4][4] = {};
    for (int k0 = 0; k0 < K; k0 += 16) {
        float4 av = *(const float4*)(Ap + k0);
        float4 wv = *(const float4*)(Wp + (size_t)k0 * N);
        As[ac + 0][ar] = av.x; As[ac + 1][ar] = av.y;
        As[ac + 2][ar] = av.z; As[ac + 3][ar] = av.w;
        *(float4*)&Bs[wr][wc] = wv;
        __syncthreads();
        #pragma unroll
        for (int kk = 0; kk < 16; ++kk) {
            const float4 a = *(const float4*)&As[kk][ty << 2];
            const float4 b = *(const float4*)&Bs[kk][tx << 2];
            const float a4[4] = {a.x, a.y, a.z, a.w};
            const float b4[4] = {b.x, b.y, b.z, b.w};
            #pragma unroll
            for (int i = 0; i < 4; ++i)
                #pragma unroll
                for (int j = 0; j < 4; ++j)
                    acc[i][j] += a4[i] * b4[j];
        }
        __syncthreads();
    }
    const int col = bn * 64 + (tx << 2);
    const float4 bi = *(const float4*)&bias[col];
    #pragma unroll
    for (int i = 0; i < 4; ++i) {
        const int row = bm * 64 + (ty << 2) + i;
        float4 o;
        o.x = acc[i][0] + bi.x; o.y = acc[i][1] + bi.y;
        o.z = acc[i][2] + bi.z; o.w = acc[i][3] + bi.w;
        if (RES) {
            const float4 rv = *(const float4*)&R[(size_t)row * N + col];
            o.x += rv.x; o.y += rv.y; o.z += rv.z; o.w += rv.w;
        }
        if (GELU) {
            o.x = gelu_exact(o.x); o.y = gelu_exact(o.y);
            o.z = gelu_exact(o.z); o.w = gelu_exact(o.w);
        }
        *(float4*)&C[(size_t)row * N + col] = o;
    }
}

// ---------------- Tiny GEMM for cs_key projections (M=10) ----------------
__global__ __launch_bounds__(256)
void gemm_small(const float* __restrict__ A, const float* __restrict__ W,
                const float* __restrict__ bias, float* __restrict__ C, int K, int N)
{
    const int m = blockIdx.x, n = threadIdx.x;
    float acc = bias[n];
    for (int k = 0; k < K; ++k) acc += A[(size_t)m * K + k] * W[(size_t)k * N + n];
    C[(size_t)m * N + n] = acc;
}

// ---------------- Hopfield attention: scores -> sparsemax -> A@V ----------
// q: (nb*L, 256) head-major cols. k,v: (nb*S, 256) or shared (S,256).
// ho out: (nb, 8, L, 32) contiguous == the mix=True reshape quirk layout.
template<int S, int SHARED_KV>
__global__ __launch_bounds__(256)
void attn_sparsemax(const float* __restrict__ q, const float* __restrict__ k,
                    const float* __restrict__ v, float* __restrict__ ho, int L)
{
    __shared__ float Ks[128][33];
    __shared__ float Vs[128][33];
    __shared__ float sc[4][128];
    const int b    = blockIdx.x >> 3;
    const int h    = blockIdx.x & 7;
    const int t    = threadIdx.x;
    const int w    = t >> 6;
    const int lane = t & 63;
    for (int idx = t; idx < S * 32; idx += 256) {
        const int j = idx >> 5, e = idx & 31;
        const size_t row = SHARED_KV ? (size_t)j : ((size_t)b * S + j);
        Ks[j][e] = k[row * 256 + h * 32 + e];
        Vs[j][e] = v[row * 256 + h * 32 + e];
    }
    __syncthreads();
    const float scale = 0.17677669529663687f;  // 1/sqrt(32)
    const int j0 = lane;
    for (int l = w; l < L; l += 4) {
        const float qreg = q[((size_t)b * L + l) * 256 + h * 32 + (lane & 31)];
        float z0 = 0.f, z1 = 0.f;
        #pragma unroll
        for (int e = 0; e < 32; ++e) {
            const float qe = __shfl(qreg, e);
            z0 += qe * Ks[j0][e];                 // rows >= S are garbage; masked below
            if (S > 64) z1 += qe * Ks[j0 + 64][e];
        }
        z0 *= scale; z1 *= scale;
        if (j0 < S) sc[w][j0] = z0;
        if (S > 64) sc[w][j0 + 64] = z1;
        __syncthreads();
        // rank (= # strictly greater) and sum of strictly-greater values
        float r0 = 0.f, sg0 = 0.f, r1 = 0.f, sg1 = 0.f;
        for (int j = 0; j < S; ++j) {
            const float zj = sc[w][j];
            if (zj > z0) { r0 += 1.f; sg0 += zj; }
            if (S > 64) { if (zj > z1) { r1 += 1.f; sg1 += zj; } }
        }
        float fcnt = 0.f, fsum = 0.f;
        const bool f0 = (j0 < S) && (1.f + (r0 + 1.f) * z0 > sg0 + z0);
        if (f0) { fcnt += 1.f; fsum += z0; }
        if (S > 64) {
            const bool f1 = (1.f + (r1 + 1.f) * z1 > sg1 + z1);
            if (f1) { fcnt += 1.f; fsum += z1; }
        }
        #pragma unroll
        for (int off = 32; off >= 1; off >>= 1) {
            fcnt += __shfl_xor(fcnt, off);
            fsum += __shfl_xor(fsum, off);
        }
        const float tau = (fsum - 1.f) / fcnt;   // support non-empty always
        if (j0 < S) sc[w][j0] = fmaxf(z0 - tau, 0.f);
        if (S > 64) sc[w][j0 + 64] = fmaxf(z1 - tau, 0.f);
        __syncthreads();
        // out_e = sum_j p_j * V[j][e]; lanes: half=lane>>5 splits j-range
        const int jc = S >> 1;
        const int half = lane >> 5, e = lane & 31;
        float acc = 0.f;
        for (int jt = 0; jt < jc; ++jt) {
            const int j = half * jc + jt;
            acc += sc[w][j] * Vs[j][e];
        }
        acc += __shfl_xor(acc, 32);
        if (lane < 32) ho[(((size_t)b * 8 + h) * L + l) * 32 + e] = acc;
        __syncthreads();
    }
}

// ---------------- LayerNorm over last dim (256) ---------------------------
__global__ __launch_bounds__(256)
void layernorm_k(const float* __restrict__ x, const float* __restrict__ g,
                 const float* __restrict__ bb, float* __restrict__ out)
{
    const int w = threadIdx.x >> 6, lane = threadIdx.x & 63;
    const size_t row = (size_t)blockIdx.x * 4 + w;
    const float4 xv = *(const float4*)&x[row * 256 + lane * 4];
    float s  = xv.x + xv.y + xv.z + xv.w;
    float sq = xv.x * xv.x + xv.y * xv.y + xv.z * xv.z + xv.w * xv.w;
    #pragma unroll
    for (int off = 32; off >= 1; off >>= 1) {
        s  += __shfl_xor(s, off);
        sq += __shfl_xor(sq, off);
    }
    const float mean = s * (1.f / 256.f);
    const float var  = sq * (1.f / 256.f) - mean * mean;
    const float rstd = rsqrtf(var + 1e-5f);
    const float4 gv = *(const float4*)&g[lane * 4];
    const float4 bv = *(const float4*)&bb[lane * 4];
    float4 o;
    o.x = (xv.x - mean) * rstd * gv.x + bv.x;
    o.y = (xv.y - mean) * rstd * gv.y + bv.y;
    o.z = (xv.z - mean) * rstd * gv.z + bv.z;
    o.w = (xv.w - mean) * rstd * gv.w + bv.w;
    *(float4*)&out[row * 256 + lane * 4] = o;
}

// ------------- (B, d1, d2, 256) -> (B, d2, d1, 256), float4 granularity ----
__global__ __launch_bounds__(256)
void transpose_bd(const float4* __restrict__ in, float4* __restrict__ out, int d1, int d2)
{
    const size_t idx = (size_t)blockIdx.x * 256 + threadIdx.x;  // grid sized exactly
    const int c = (int)(idx & 63);
    const size_t r = idx >> 6;
    const int j = (int)(r % d2);
    const size_t r2 = r / d2;
    const int i = (int)(r2 % d1);
    const int bb = (int)(r2 / d1);
    out[(((size_t)bb * d2 + j) * d1 + i) * 64 + c] = in[idx];
}

extern "C" void kernel_launch(void* const* d_in, const int* in_sizes, int n_in,
                              void* d_out, int out_size, void* d_ws, size_t ws_size,
                              hipStream_t stream)
{
    const float* x      = (const float*)d_in[0];
    const float* ct_wq  = (const float*)d_in[1];  const float* ct_bq = (const float*)d_in[2];
    const float* ct_wk  = (const float*)d_in[3];  const float* ct_bk = (const float*)d_in[4];
    const float* ct_wv  = (const float*)d_in[5];  const float* ct_bv = (const float*)d_in[6];
    const float* ct_wo  = (const float*)d_in[7];  const float* ct_bo = (const float*)d_in[8];
    const float* cs_wq  = (const float*)d_in[9];  const float* cs_bq = (const float*)d_in[10];
    const float* cs_wk  = (const float*)d_in[11]; const float* cs_bk = (const float*)d_in[12];
    const float* cs_wv  = (const float*)d_in[13]; const float* cs_bv = (const float*)d_in[14];
    const float* cs_wo  = (const float*)d_in[15]; const float* cs_bo = (const float*)d_in[16];
    const float* hp_wq  = (const float*)d_in[17]; const float* hp_bq = (const float*)d_in[18];
    const float* hp_wk  = (const float*)d_in[19]; const float* hp_bk = (const float*)d_in[20];
    const float* hp_wv  = (const float*)d_in[21]; const float* hp_bv = (const float*)d_in[22];
    const float* hp_wo  = (const float*)d_in[23]; const float* hp_bo = (const float*)d_in[24];
    const float* cs_key = (const float*)d_in[25];
    const float* ln_g   = (const float*)d_in[26]; const float* ln_b   = (const float*)d_in[27];
    const float* m1_w1  = (const float*)d_in[28]; const float* m1_b1  = (const float*)d_in[29];
    const float* m1_w2  = (const float*)d_in[30]; const float* m1_b2  = (const float*)d_in[31];
    const float* m2_w1  = (const float*)d_in[32]; const float* m2_b1  = (const float*)d_in[33];
    const float* m2_w2  = (const float*)d_in[34]; const float* m2_b2  = (const float*)d_in[35];

    const size_t SL = 8388608;  // floats per 33.5MB slot
    float* P0 = (float*)d_ws;
    float* P1 = P0 + SL;
    float* P2 = P0 + 2 * SL;
    float* P3 = P0 + 3 * SL;
    float* P4 = P0 + 4 * SL;
    float* kp2 = P0 + 5 * SL;      // (10,256)
    float* v2  = kp2 + 2560;       // (10,256)

    const dim3 blk(256);
    const int M = 32768;

    // ---- time-stage Hopfield (ct): S=128, L=128, nb=256 ----
    gemm64<0,0><<<dim3(4, 512), blk, 0, stream>>>(x,  ct_wq, ct_bq, nullptr, P0, M, 256, 256); // q1
    gemm64<0,0><<<dim3(4, 512), blk, 0, stream>>>(x,  ct_wk, ct_bk, nullptr, P1, M, 256, 256); // k1
    gemm64<0,0><<<dim3(4, 512), blk, 0, stream>>>(P1, ct_wv, ct_bv, nullptr, P2, M, 256, 256); // v1 = V(k1)
    attn_sparsemax<128,0><<<dim3(256 * 8), blk, 0, stream>>>(P0, P1, P2, P3, 128);             // ho1
    gemm64<0,1><<<dim3(4, 512), blk, 0, stream>>>(P3, ct_wo, ct_bo, x, P1, M, 256, 256);       // dim_in = x + enc

    // ---- MLP1 (chunked hidden so it fits one slot) ----
    for (int c = 0; c < 4; ++c) {
        const float* src = P1 + (size_t)c * 8192 * 256;
        gemm64<1,0><<<dim3(16, 128), blk, 0, stream>>>(src, m1_w1, m1_b1, nullptr, P0, 8192, 1024, 256);
        gemm64<0,1><<<dim3(4, 128), blk, 0, stream>>>(P0, m1_w2, m1_b2, src,
                                                      P2 + (size_t)c * 8192 * 256, 8192, 256, 1024);
    }

    // ---- (b,ts,seg,D) -> (b,seg,ts,D) ----
    transpose_bd<<<dim3(8192), blk, 0, stream>>>((const float4*)P2, (float4*)P3, 64, 128);     // series_in

    // ---- cs Hopfield: shared K/V from cs_key, S=10, L=64, nb=512 ----
    gemm64<0,0><<<dim3(4, 512), blk, 0, stream>>>(P3, cs_wq, cs_bq, nullptr, P0, M, 256, 256); // q2
    gemm_small<<<dim3(10), blk, 0, stream>>>(cs_key, cs_wk, cs_bk, kp2, 256, 256);             // kproj2
    gemm_small<<<dim3(10), blk, 0, stream>>>(kp2,    cs_wv, cs_bv, v2,  256, 256);             // v2
    attn_sparsemax<10,1><<<dim3(512 * 8), blk, 0, stream>>>(P0, kp2, v2, P1, 64);              // ho2
    gemm64<0,0><<<dim3(4, 512), blk, 0, stream>>>(P1, cs_wo, cs_bo, nullptr, P2, M, 256, 256); // series_h

    // ---- hp Hopfield: self, S=64, L=64, nb=512 ----
    gemm64<0,0><<<dim3(4, 512), blk, 0, stream>>>(P3, hp_wq, hp_bq, nullptr, P0, M, 256, 256); // q3
    gemm64<0,0><<<dim3(4, 512), blk, 0, stream>>>(P3, hp_wk, hp_bk, nullptr, P1, M, 256, 256); // k3
    gemm64<0,0><<<dim3(4, 512), blk, 0, stream>>>(P1, hp_wv, hp_bv, nullptr, P3, M, 256, 256); // v3 (overwrites series_in)
    attn_sparsemax<64,0><<<dim3(512 * 8), blk, 0, stream>>>(P0, P1, P3, P4, 64);               // ho3
    gemm64<0,1><<<dim3(4, 512), blk, 0, stream>>>(P4, hp_wo, hp_bo, P2, P0, M, 256, 256);      // series_h + pooled_h

    // ---- LN + MLP2 ----
    layernorm_k<<<dim3(8192), blk, 0, stream>>>(P0, ln_g, ln_b, P1);                           // dim_enc
    for (int c = 0; c < 4; ++c) {
        const float* src = P1 + (size_t)c * 8192 * 256;
        gemm64<1,0><<<dim3(16, 128), blk, 0, stream>>>(src, m2_w1, m2_b1, nullptr, P2, 8192, 1024, 256);
        gemm64<0,1><<<dim3(4, 128), blk, 0, stream>>>(P2, m2_w2, m2_b2, src,
                                                      P3 + (size_t)c * 8192 * 256, 8192, 256, 1024);
    }

    // ---- (b,seg,ts,D) -> (b,ts,seg,D) into d_out ----
    transpose_bd<<<dim3(8192), blk, 0, stream>>>((const float4*)P3, (float4*)d_out, 128, 64);
}

// Round 2
// 2087.361 us; speedup vs baseline: 1.6273x; 1.6273x over previous
//
#include <hip/hip_runtime.h>
#include <math.h>

// STHM layer. B=4, TS=64, SEG=128, D=256, H=8, dh=32, DFF=1024.
// GEMMs: split-bf16 (hi+lo) MFMA, fp32-class accuracy. Sparsemax: Michelot fixed-point.

typedef unsigned short u16;
typedef unsigned int u32;
typedef __attribute__((ext_vector_type(8))) short s8v;   // 8 bf16 (4 VGPRs) MFMA frag
typedef __attribute__((ext_vector_type(4))) float f4v;   // MFMA accumulator

__device__ __forceinline__ float gelu_exact(float x) {
    return 0.5f * x * (1.0f + erff(x * 0.70710678118654752f));
}
__device__ __forceinline__ u16 bf16_rne(float f) {
    u32 u = __float_as_uint(f);
    return (u16)((u + 0x7FFFu + ((u >> 16) & 1u)) >> 16);
}
__device__ __forceinline__ float bf16_to_f(u16 h) {
    return __uint_as_float((u32)h << 16);
}

// ---- Weight prep: W(K,N fp32 row-major) -> Wh/Wl (N,K bf16 hi/lo, transposed) ----
__global__ __launch_bounds__(256)
void wconv(const float* __restrict__ W, u16* __restrict__ Wh, u16* __restrict__ Wl,
           int K, int N)
{
    __shared__ float tile[32][33];
    const int t = threadIdx.x;
    const int n0 = blockIdx.x * 32, k0 = blockIdx.y * 32;
    const int r = t >> 3, c = (t & 7) << 2;
    const float4 f = *(const float4*)&W[(size_t)(k0 + r) * N + n0 + c];
    tile[r][c] = f.x; tile[r][c + 1] = f.y; tile[r][c + 2] = f.z; tile[r][c + 3] = f.w;
    __syncthreads();
    u32 hp[2], lp[2];
    #pragma unroll
    for (int p = 0; p < 2; ++p) {
        u16 h[2], l[2];
        #pragma unroll
        for (int e = 0; e < 2; ++e) {
            const float fv = tile[c + p * 2 + e][r];
            h[e] = bf16_rne(fv);
            l[e] = bf16_rne(fv - bf16_to_f(h[e]));
        }
        hp[p] = (u32)h[0] | ((u32)h[1] << 16);
        lp[p] = (u32)l[0] | ((u32)l[1] << 16);
    }
    uint2 hv; hv.x = hp[0]; hv.y = hp[1];
    uint2 lv; lv.x = lp[0]; lv.y = lp[1];
    *(uint2*)&Wh[(size_t)(n0 + r) * K + k0 + c] = hv;
    *(uint2*)&Wl[(size_t)(n0 + r) * K + k0 + c] = lv;
}

// ---- Split-bf16 MFMA GEMM: C = A(M,K fp32) @ W(K,N) + bias [+R] [gelu] ----
// BM=BN=128, BK=32; 4 waves, each a 64x64 quadrant of 16x16 MFMA tiles.
template<int GELU, int RES>
__global__ __launch_bounds__(256)
void gemm_mfma(const float* __restrict__ A, const u16* __restrict__ Wh,
               const u16* __restrict__ Wl, const float* __restrict__ bias,
               const float* __restrict__ R, float* __restrict__ C,
               int M, int N, int K)
{
    __shared__ u16 Ah[128][40], Al[128][40], Bh[128][40], Bl[128][40];  // +8 pad, 80B rows (16B-aligned)
    const int t = threadIdx.x;
    const int bn = blockIdx.x, bm = blockIdx.y;
    const int w = t >> 6, lane = t & 63;
    const int wy = w >> 1, wx = w & 1;
    const int lm = lane & 15, kq = ((lane >> 4) & 3) << 3;
    const int ar = t >> 1, ac = (t & 1) << 4;   // staging: 128 rows x two 16-elem halves
    const float* Ap = A + (size_t)(bm * 128 + ar) * K + ac;
    const u16* Whp = Wh + (size_t)(bn * 128 + ar) * K + ac;
    const u16* Wlp = Wl + (size_t)(bn * 128 + ar) * K + ac;
    f4v acc[4][4] = {};
    for (int k0 = 0; k0 < K; k0 += 32) {
        u32 hw[8], lw[8];
        #pragma unroll
        for (int vv = 0; vv < 4; ++vv) {
            const float4 f = *(const float4*)(Ap + k0 + (vv << 2));
            const float fs[4] = {f.x, f.y, f.z, f.w};
            u16 hh[4], ll[4];
            #pragma unroll
            for (int e = 0; e < 4; ++e) {
                hh[e] = bf16_rne(fs[e]);
                ll[e] = bf16_rne(fs[e] - bf16_to_f(hh[e]));
            }
            hw[vv * 2]     = (u32)hh[0] | ((u32)hh[1] << 16);
            hw[vv * 2 + 1] = (u32)hh[2] | ((u32)hh[3] << 16);
            lw[vv * 2]     = (u32)ll[0] | ((u32)ll[1] << 16);
            lw[vv * 2 + 1] = (u32)ll[2] | ((u32)ll[3] << 16);
        }
        *(uint4*)&Ah[ar][ac]     = make_uint4(hw[0], hw[1], hw[2], hw[3]);
        *(uint4*)&Ah[ar][ac + 8] = make_uint4(hw[4], hw[5], hw[6], hw[7]);
        *(uint4*)&Al[ar][ac]     = make_uint4(lw[0], lw[1], lw[2], lw[3]);
        *(uint4*)&Al[ar][ac + 8] = make_uint4(lw[4], lw[5], lw[6], lw[7]);
        *(uint4*)&Bh[ar][ac]     = *(const uint4*)(Whp + k0);
        *(uint4*)&Bh[ar][ac + 8] = *(const uint4*)(Whp + k0 + 8);
        *(uint4*)&Bl[ar][ac]     = *(const uint4*)(Wlp + k0);
        *(uint4*)&Bl[ar][ac + 8] = *(const uint4*)(Wlp + k0 + 8);
        __syncthreads();
        s8v fah[4], fal[4], fbh[4], fbl[4];
        #pragma unroll
        for (int i = 0; i < 4; ++i) {
            fah[i] = *(const s8v*)&Ah[wy * 64 + i * 16 + lm][kq];
            fal[i] = *(const s8v*)&Al[wy * 64 + i * 16 + lm][kq];
        }
        #pragma unroll
        for (int j = 0; j < 4; ++j) {
            fbh[j] = *(const s8v*)&Bh[wx * 64 + j * 16 + lm][kq];
            fbl[j] = *(const s8v*)&Bl[wx * 64 + j * 16 + lm][kq];
        }
        #pragma unroll
        for (int i = 0; i < 4; ++i)
            #pragma unroll
            for (int j = 0; j < 4; ++j) {
                acc[i][j] = __builtin_amdgcn_mfma_f32_16x16x32_bf16(fal[i], fbh[j], acc[i][j], 0, 0, 0);
                acc[i][j] = __builtin_amdgcn_mfma_f32_16x16x32_bf16(fah[i], fbl[j], acc[i][j], 0, 0, 0);
                acc[i][j] = __builtin_amdgcn_mfma_f32_16x16x32_bf16(fah[i], fbh[j], acc[i][j], 0, 0, 0);
            }
        __syncthreads();
    }
    const int q4 = ((lane >> 4) & 3) << 2;
    #pragma unroll
    for (int j = 0; j < 4; ++j) {
        const int col = bn * 128 + wx * 64 + j * 16 + lm;
        const float bj = bias[col];
        #pragma unroll
        for (int i = 0; i < 4; ++i) {
            const int row0 = bm * 128 + wy * 64 + i * 16 + q4;
            #pragma unroll
            for (int r = 0; r < 4; ++r) {
                float val = acc[i][j][r] + bj;
                if (RES) val += R[(size_t)(row0 + r) * N + col];
                if (GELU) val = gelu_exact(val);
                C[(size_t)(row0 + r) * N + col] = val;
            }
        }
    }
}

// ---- Tiny fp32 GEMM for cs_key projections (M=10), exact ----
__global__ __launch_bounds__(256)
void gemm_small(const float* __restrict__ A, const float* __restrict__ W,
                const float* __restrict__ bias, float* __restrict__ C, int K, int N)
{
    const int m = blockIdx.x, n = threadIdx.x;
    float acc = bias[n];
    for (int k = 0; k < K; ++k) acc += A[(size_t)m * K + k] * W[(size_t)k * N + n];
    C[(size_t)m * N + n] = acc;
}

// ---- Hopfield attention: scores -> sparsemax (Michelot) -> A@V ----
// ho out layout (nb, 8, L, 32) == the mix=True reshape quirk.
template<int S, int SHARED_KV>
__global__ __launch_bounds__(256)
void attn_sparsemax(const float* __restrict__ q, const float* __restrict__ k,
                    const float* __restrict__ v, float* __restrict__ ho, int L)
{
    __shared__ float Ks[S][33];
    __shared__ float Vs[S][33];
    __shared__ float sc[4][S];
    const int b = blockIdx.x >> 3, h = blockIdx.x & 7;
    const int t = threadIdx.x, w = t >> 6, lane = t & 63;
    for (int idx = t; idx < S * 32; idx += 256) {
        const int j = idx >> 5, e = idx & 31;
        const size_t row = SHARED_KV ? (size_t)j : ((size_t)b * S + j);
        Ks[j][e] = k[row * 256 + h * 32 + e];
        Vs[j][e] = v[row * 256 + h * 32 + e];
    }
    __syncthreads();
    const float scale = 0.17677669529663687f;  // 1/sqrt(32)
    const int j0 = lane;
    const bool valid0 = (j0 < S);
    const int jr0 = valid0 ? j0 : (S - 1);
    for (int l = w; l < L; l += 4) {
        const float qreg = q[((size_t)b * L + l) * 256 + h * 32 + (lane & 31)];
        float z0 = 0.f, z1 = 0.f;
        #pragma unroll
        for (int e = 0; e < 32; ++e) {
            const float qe = __shfl(qreg, e);
            z0 = fmaf(qe, Ks[jr0][e], z0);
            if (S > 64) z1 = fmaf(qe, Ks[j0 + 64][e], z1);
        }
        z0 *= scale; z1 *= scale;
        // Michelot fixed-point: tau = (sum_active - 1)/|active|; active = {z > tau}.
        float kprev = -1.f, tau = -3.0e38f;
        for (int it = 0; it <= S; ++it) {
            float cnt = 0.f, sum = 0.f;
            if (valid0 && z0 > tau) { cnt = 1.f; sum = z0; }
            if (S > 64 && z1 > tau) { cnt += 1.f; sum += z1; }
            #pragma unroll
            for (int off = 32; off >= 1; off >>= 1) {
                cnt += __shfl_xor(cnt, off);
                sum += __shfl_xor(sum, off);
            }
            if (cnt == kprev) break;   // active set unchanged -> tau final
            kprev = cnt;
            tau = (sum - 1.f) / cnt;
        }
        if (valid0) sc[w][j0] = fmaxf(z0 - tau, 0.f);
        if (S > 64) sc[w][j0 + 64] = fmaxf(z1 - tau, 0.f);
        __syncthreads();
        const int half = lane >> 5, e = lane & 31;
        float acc = 0.f;
        for (int jt = 0; jt < (S >> 1); ++jt) {
            const int j = half * (S >> 1) + jt;
            acc = fmaf(sc[w][j], Vs[j][e], acc);
        }
        acc += __shfl_xor(acc, 32);
        if (lane < 32) ho[(((size_t)b * 8 + h) * L + l) * 32 + e] = acc;
        __syncthreads();
    }
}

// ---- LayerNorm over last dim (256) ----
__global__ __launch_bounds__(256)
void layernorm_k(const float* __restrict__ x, const float* __restrict__ g,
                 const float* __restrict__ bb, float* __restrict__ out)
{
    const int w = threadIdx.x >> 6, lane = threadIdx.x & 63;
    const size_t row = (size_t)blockIdx.x * 4 + w;
    const float4 xv = *(const float4*)&x[row * 256 + lane * 4];
    float s  = xv.x + xv.y + xv.z + xv.w;
    float sq = xv.x * xv.x + xv.y * xv.y + xv.z * xv.z + xv.w * xv.w;
    #pragma unroll
    for (int off = 32; off >= 1; off >>= 1) {
        s  += __shfl_xor(s, off);
        sq += __shfl_xor(sq, off);
    }
    const float mean = s * (1.f / 256.f);
    const float var  = sq * (1.f / 256.f) - mean * mean;
    const float rstd = rsqrtf(var + 1e-5f);
    const float4 gv = *(const float4*)&g[lane * 4];
    const float4 bv = *(const float4*)&bb[lane * 4];
    float4 o;
    o.x = (xv.x - mean) * rstd * gv.x + bv.x;
    o.y = (xv.y - mean) * rstd * gv.y + bv.y;
    o.z = (xv.z - mean) * rstd * gv.z + bv.z;
    o.w = (xv.w - mean) * rstd * gv.w + bv.w;
    *(float4*)&out[row * 256 + lane * 4] = o;
}

// ---- (B, d1, d2, 256) -> (B, d2, d1, 256), float4 granularity ----
__global__ __launch_bounds__(256)
void transpose_bd(const float4* __restrict__ in, float4* __restrict__ out, int d1, int d2)
{
    const size_t idx = (size_t)blockIdx.x * 256 + threadIdx.x;
    const int c = (int)(idx & 63);
    const size_t r = idx >> 6;
    const int j = (int)(r % d2);
    const size_t r2 = r / d2;
    const int i = (int)(r2 % d1);
    const int bb = (int)(r2 / d1);
    out[(((size_t)bb * d2 + j) * d1 + i) * 64 + c] = in[idx];
}

extern "C" void kernel_launch(void* const* d_in, const int* in_sizes, int n_in,
                              void* d_out, int out_size, void* d_ws, size_t ws_size,
                              hipStream_t stream)
{
    const float* x      = (const float*)d_in[0];
    const float* ct_wq  = (const float*)d_in[1];  const float* ct_bq = (const float*)d_in[2];
    const float* ct_wk  = (const float*)d_in[3];  const float* ct_bk = (const float*)d_in[4];
    const float* ct_wv  = (const float*)d_in[5];  const float* ct_bv = (const float*)d_in[6];
    const float* ct_wo  = (const float*)d_in[7];  const float* ct_bo = (const float*)d_in[8];
    const float* cs_wq  = (const float*)d_in[9];  const float* cs_bq = (const float*)d_in[10];
    const float* cs_wk  = (const float*)d_in[11]; const float* cs_bk = (const float*)d_in[12];
    const float* cs_wv  = (const float*)d_in[13]; const float* cs_bv = (const float*)d_in[14];
    const float* cs_wo  = (const float*)d_in[15]; const float* cs_bo = (const float*)d_in[16];
    const float* hp_wq  = (const float*)d_in[17]; const float* hp_bq = (const float*)d_in[18];
    const float* hp_wk  = (const float*)d_in[19]; const float* hp_bk = (const float*)d_in[20];
    const float* hp_wv  = (const float*)d_in[21]; const float* hp_bv = (const float*)d_in[22];
    const float* hp_wo  = (const float*)d_in[23]; const float* hp_bo = (const float*)d_in[24];
    const float* cs_key = (const float*)d_in[25];
    const float* ln_g   = (const float*)d_in[26]; const float* ln_b   = (const float*)d_in[27];
    const float* m1_w1  = (const float*)d_in[28]; const float* m1_b1  = (const float*)d_in[29];
    const float* m1_w2  = (const float*)d_in[30]; const float* m1_b2  = (const float*)d_in[31];
    const float* m2_w1  = (const float*)d_in[32]; const float* m2_b1  = (const float*)d_in[33];
    const float* m2_w2  = (const float*)d_in[34]; const float* m2_b2  = (const float*)d_in[35];

    const size_t SL = 8388608;  // floats per 33.5MB slot
    float* P0 = (float*)d_ws;
    float* P1 = P0 + SL;
    float* P2 = P0 + 2 * SL;
    float* P3 = P0 + 3 * SL;
    u16*   WT = (u16*)(P0 + 4 * SL);           // 6.8 MB of split weights
    float* kp2 = P0 + 4 * SL + 4194304;        // (10,256)
    float* v2  = kp2 + 2560;                   // (10,256)
    float* OUTS = (float*)d_out;               // scratch mid-flight, overwritten at end

    const dim3 blk(256);
    const int M = 32768, Mc = 16384;

    // ---- weight prep: 14 matrices -> transposed bf16 hi/lo ----
    u16* w_h[14]; u16* w_l[14];
    u16* wt = WT;
    const float* wsrc[14] = {ct_wq, ct_wk, ct_wv, ct_wo, cs_wq, cs_wo,
                             hp_wq, hp_wk, hp_wv, hp_wo, m1_w1, m1_w2, m2_w1, m2_w2};
    const int wK[14] = {256,256,256,256,256,256,256,256,256,256,256,1024,256,1024};
    const int wN[14] = {256,256,256,256,256,256,256,256,256,256,1024,256,1024,256};
    for (int i = 0; i < 14; ++i) {
        w_h[i] = wt; w_l[i] = wt + (size_t)wK[i] * wN[i];
        wt += 2 * (size_t)wK[i] * wN[i];
        wconv<<<dim3(wN[i] / 32, wK[i] / 32), blk, 0, stream>>>(wsrc[i], w_h[i], w_l[i], wK[i], wN[i]);
    }

    auto G = [&](const float* A, int wi, const float* bias, const float* R,
                 float* C, int m, int n, int kk, int gelu) {
        dim3 g(n / 128, m / 128);
        if (gelu)   gemm_mfma<1,0><<<g, blk, 0, stream>>>(A, w_h[wi], w_l[wi], bias, nullptr, C, m, n, kk);
        else if (R) gemm_mfma<0,1><<<g, blk, 0, stream>>>(A, w_h[wi], w_l[wi], bias, R, C, m, n, kk);
        else        gemm_mfma<0,0><<<g, blk, 0, stream>>>(A, w_h[wi], w_l[wi], bias, nullptr, C, m, n, kk);
    };

    // ---- ct Hopfield: S=128, L=128, nb=256 ----
    G(x,  0, ct_bq, nullptr, P0, M, 256, 256, 0);                                  // q1
    G(x,  1, ct_bk, nullptr, P1, M, 256, 256, 0);                                  // k1
    G(P1, 2, ct_bv, nullptr, P2, M, 256, 256, 0);                                  // v1 = V(k1)
    attn_sparsemax<128,0><<<dim3(2048), blk, 0, stream>>>(P0, P1, P2, P3, 128);    // ho1
    G(P3, 3, ct_bo, x, P0, M, 256, 256, 0);                                        // dim_in = x + enc

    // ---- MLP1 (2 chunks of 16384 rows; hidden spans P2..P3) ----
    for (int c = 0; c < 2; ++c) {
        float* src = P0 + (size_t)c * Mc * 256;
        G(src, 10, m1_b1, nullptr, P2, Mc, 1024, 256, 1);
        G(P2,  11, m1_b2, src, P1 + (size_t)c * Mc * 256, Mc, 256, 1024, 0);
    }

    // ---- (b,ts,seg,D) -> (b,seg,ts,D) ----
    transpose_bd<<<dim3(8192), blk, 0, stream>>>((const float4*)P1, (float4*)P0, 64, 128); // series_in

    // ---- hp Hopfield: self, S=64, L=64, nb=512 (ho3 -> d_out scratch) ----
    G(P0, 6, hp_bq, nullptr, P1, M, 256, 256, 0);                                  // q3
    G(P0, 7, hp_bk, nullptr, P2, M, 256, 256, 0);                                  // k3
    G(P2, 8, hp_bv, nullptr, P3, M, 256, 256, 0);                                  // v3
    attn_sparsemax<64,0><<<dim3(4096), blk, 0, stream>>>(P1, P2, P3, OUTS, 64);    // ho3
    G(OUTS, 9, hp_bo, nullptr, P2, M, 256, 256, 0);                                // pooled_h

    // ---- cs Hopfield: shared K/V from cs_key, S=10, L=64 ----
    G(P0, 4, cs_bq, nullptr, P1, M, 256, 256, 0);                                  // q2
    gemm_small<<<dim3(10), blk, 0, stream>>>(cs_key, cs_wk, cs_bk, kp2, 256, 256); // kproj2
    gemm_small<<<dim3(10), blk, 0, stream>>>(kp2,    cs_wv, cs_bv, v2,  256, 256); // v2
    attn_sparsemax<10,1><<<dim3(4096), blk, 0, stream>>>(P1, kp2, v2, P3, 64);     // ho2
    G(P3, 5, cs_bo, P2, P0, M, 256, 256, 0);                                       // series_h + pooled_h

    // ---- LN + MLP2 ----
    layernorm_k<<<dim3(8192), blk, 0, stream>>>(P0, ln_g, ln_b, P1);               // dim_enc
    for (int c = 0; c < 2; ++c) {
        float* src = P1 + (size_t)c * Mc * 256;
        G(src, 12, m2_b1, nullptr, P2, Mc, 1024, 256, 1);
        G(P2,  13, m2_b2, src, P0 + (size_t)c * Mc * 256, Mc, 256, 1024, 0);
    }

    // ---- (b,seg,ts,D) -> (b,ts,seg,D) into d_out ----
    transpose_bd<<<dim3(8192), blk, 0, stream>>>((const float4*)P0, (float4*)OUTS, 128, 64);
}

// Round 3
// 1424.235 us; speedup vs baseline: 2.3850x; 1.4656x over previous
//
#include <hip/hip_runtime.h>
#include <math.h>

// STHM layer. B=4, TS=64, SEG=128, D=256, H=8, dh=32, DFF=1024.
// All activations stored as split-bf16 (hi/lo) planes; GEMMs + attention on MFMA.

typedef unsigned short u16;
typedef unsigned int u32;
typedef __attribute__((ext_vector_type(8))) short s8v;   // 8 bf16 (4 VGPRs) MFMA frag
typedef __attribute__((ext_vector_type(4))) float f4v;   // MFMA accumulator

#define MFMA16 __builtin_amdgcn_mfma_f32_16x16x32_bf16

__device__ __forceinline__ float gelu_exact(float x) {
    return 0.5f * x * (1.0f + erff(x * 0.70710678118654752f));
}
__device__ __forceinline__ u16 bf16_rne(float f) {
    u32 u = __float_as_uint(f);
    return (u16)((u + 0x7FFFu + ((u >> 16) & 1u)) >> 16);
}
__device__ __forceinline__ float bf16_to_f(u16 h) {
    return __uint_as_float((u32)h << 16);
}

// ---- Weight prep: W(K,N fp32 row-major) -> Wh/Wl (N,K bf16 hi/lo, transposed) ----
__global__ __launch_bounds__(256)
void wconv(const float* __restrict__ W, u16* __restrict__ Wh, u16* __restrict__ Wl,
           int K, int N)
{
    __shared__ float tile[32][33];
    const int t = threadIdx.x;
    const int n0 = blockIdx.x * 32, k0 = blockIdx.y * 32;
    const int r = t >> 3, c = (t & 7) << 2;
    const float4 f = *(const float4*)&W[(size_t)(k0 + r) * N + n0 + c];
    tile[r][c] = f.x; tile[r][c + 1] = f.y; tile[r][c + 2] = f.z; tile[r][c + 3] = f.w;
    __syncthreads();
    u32 hp[2], lp[2];
    #pragma unroll
    for (int p = 0; p < 2; ++p) {
        u16 h[2], l[2];
        #pragma unroll
        for (int e = 0; e < 2; ++e) {
            const float fv = tile[c + p * 2 + e][r];
            h[e] = bf16_rne(fv);
            l[e] = bf16_rne(fv - bf16_to_f(h[e]));
        }
        hp[p] = (u32)h[0] | ((u32)h[1] << 16);
        lp[p] = (u32)l[0] | ((u32)l[1] << 16);
    }
    uint2 hv; hv.x = hp[0]; hv.y = hp[1];
    uint2 lv; lv.x = lp[0]; lv.y = lp[1];
    *(uint2*)&Wh[(size_t)(n0 + r) * K + k0 + c] = hv;
    *(uint2*)&Wl[(size_t)(n0 + r) * K + k0 + c] = lv;
}

// ---- fp32 tensor -> hi/lo bf16 planes (8 elems/thread) ----
__global__ __launch_bounds__(256)
void split_f32(const float* __restrict__ x, u16* __restrict__ xh, u16* __restrict__ xl)
{
    const size_t base = ((size_t)blockIdx.x * 256 + threadIdx.x) * 8;
    const float4 a = *(const float4*)(x + base);
    const float4 b = *(const float4*)(x + base + 4);
    const float fs[8] = {a.x, a.y, a.z, a.w, b.x, b.y, b.z, b.w};
    __align__(16) u16 hh[8], ll[8];
    #pragma unroll
    for (int i = 0; i < 8; ++i) {
        hh[i] = bf16_rne(fs[i]);
        ll[i] = bf16_rne(fs[i] - bf16_to_f(hh[i]));
    }
    *(uint4*)(xh + base) = *(const uint4*)hh;
    *(uint4*)(xl + base) = *(const uint4*)ll;
}

// ---- Split-bf16 MFMA GEMM: C = A(M,K) @ W(K,N) + bias [+R] [gelu] -> hi/lo planes ----
// A as hi/lo planes (M,K); W as hi/lo (N,K). BM=BN=128, BK=32; 4 waves, 64x64 quadrants.
// Operand roles: MFMA A=weights (D.row=out-col), B=activations (D.col=act-row):
// per lane the 4 acc regs are 4 CONSECUTIVE out-cols -> packed 8B stores.
template<int GELU, int RESMODE>   // RESMODE: 0 none, 1 fp32 tensor, 2 split pair
__global__ __launch_bounds__(256)
void gemm_mfma(const u16* __restrict__ Ah, const u16* __restrict__ Al,
               const u16* __restrict__ Wh, const u16* __restrict__ Wl,
               const float* __restrict__ bias, const float* __restrict__ Rf,
               const u16* __restrict__ Rh, const u16* __restrict__ Rl,
               u16* __restrict__ Ch, u16* __restrict__ Cl,
               int M, int N, int K)
{
    __shared__ __align__(16) u16 As0[128 * 32], As1[128 * 32];
    __shared__ __align__(16) u16 Ws0[128 * 32], Ws1[128 * 32];
    const int t = threadIdx.x;
    const int bn = blockIdx.x, bm = blockIdx.y;
    const int w = t >> 6, lane = t & 63;
    const int wy = w >> 1, wx = w & 1;
    const int lm = lane & 15, quad = lane >> 4, kq = quad << 3;
    const int sr = t >> 1, sc = (t & 1) << 4;
    const size_t abase = (size_t)(bm * 128 + sr) * K + sc;
    const size_t wbase = (size_t)(bn * 128 + sr) * K + sc;
    f4v acc[4][4] = {};   // [ic: out-col tile][jr: act-row tile]
    for (int k0 = 0; k0 < K; k0 += 32) {
        *(uint4*)&As0[sr * 32 + sc]     = *(const uint4*)(Ah + abase + k0);
        *(uint4*)&As0[sr * 32 + sc + 8] = *(const uint4*)(Ah + abase + k0 + 8);
        *(uint4*)&As1[sr * 32 + sc]     = *(const uint4*)(Al + abase + k0);
        *(uint4*)&As1[sr * 32 + sc + 8] = *(const uint4*)(Al + abase + k0 + 8);
        *(uint4*)&Ws0[sr * 32 + sc]     = *(const uint4*)(Wh + wbase + k0);
        *(uint4*)&Ws0[sr * 32 + sc + 8] = *(const uint4*)(Wh + wbase + k0 + 8);
        *(uint4*)&Ws1[sr * 32 + sc]     = *(const uint4*)(Wl + wbase + k0);
        *(uint4*)&Ws1[sr * 32 + sc + 8] = *(const uint4*)(Wl + wbase + k0 + 8);
        __syncthreads();
        s8v fw0[4], fw1[4], fa0[4], fa1[4];
        #pragma unroll
        for (int i = 0; i < 4; ++i) {
            fw0[i] = *(const s8v*)&Ws0[(wx * 64 + i * 16 + lm) * 32 + kq];
            fw1[i] = *(const s8v*)&Ws1[(wx * 64 + i * 16 + lm) * 32 + kq];
            fa0[i] = *(const s8v*)&As0[(wy * 64 + i * 16 + lm) * 32 + kq];
            fa1[i] = *(const s8v*)&As1[(wy * 64 + i * 16 + lm) * 32 + kq];
        }
        #pragma unroll
        for (int ic = 0; ic < 4; ++ic)
            #pragma unroll
            for (int jr = 0; jr < 4; ++jr) {
                acc[ic][jr] = MFMA16(fw1[ic], fa0[jr], acc[ic][jr], 0, 0, 0);
                acc[ic][jr] = MFMA16(fw0[ic], fa1[jr], acc[ic][jr], 0, 0, 0);
                acc[ic][jr] = MFMA16(fw0[ic], fa0[jr], acc[ic][jr], 0, 0, 0);
            }
        __syncthreads();
    }
    #pragma unroll
    for (int ic = 0; ic < 4; ++ic) {
        const int col0 = bn * 128 + wx * 64 + ic * 16 + (quad << 2);
        const float4 bv = *(const float4*)&bias[col0];
        #pragma unroll
        for (int jr = 0; jr < 4; ++jr) {
            const int row = bm * 128 + wy * 64 + jr * 16 + lm;
            const size_t o = (size_t)row * N + col0;
            float v[4] = {acc[ic][jr][0] + bv.x, acc[ic][jr][1] + bv.y,
                          acc[ic][jr][2] + bv.z, acc[ic][jr][3] + bv.w};
            if (RESMODE == 1) {
                const float4 rv = *(const float4*)(Rf + o);
                v[0] += rv.x; v[1] += rv.y; v[2] += rv.z; v[3] += rv.w;
            } else if (RESMODE == 2) {
                const uint2 rh = *(const uint2*)(Rh + o);
                const uint2 rl = *(const uint2*)(Rl + o);
                v[0] += bf16_to_f((u16)(rh.x & 0xFFFFu)) + bf16_to_f((u16)(rl.x & 0xFFFFu));
                v[1] += bf16_to_f((u16)(rh.x >> 16))     + bf16_to_f((u16)(rl.x >> 16));
                v[2] += bf16_to_f((u16)(rh.y & 0xFFFFu)) + bf16_to_f((u16)(rl.y & 0xFFFFu));
                v[3] += bf16_to_f((u16)(rh.y >> 16))     + bf16_to_f((u16)(rl.y >> 16));
            }
            if (GELU) {
                #pragma unroll
                for (int r = 0; r < 4; ++r) v[r] = gelu_exact(v[r]);
            }
            u16 hh[4], ll[4];
            #pragma unroll
            for (int r = 0; r < 4; ++r) {
                hh[r] = bf16_rne(v[r]);
                ll[r] = bf16_rne(v[r] - bf16_to_f(hh[r]));
            }
            uint2 hp, lp;
            hp.x = (u32)hh[0] | ((u32)hh[1] << 16); hp.y = (u32)hh[2] | ((u32)hh[3] << 16);
            lp.x = (u32)ll[0] | ((u32)ll[1] << 16); lp.y = (u32)ll[2] | ((u32)ll[3] << 16);
            *(uint2*)(Ch + o) = hp;
            *(uint2*)(Cl + o) = lp;
        }
    }
}

// ---- Tiny exact fp32 GEMM for cs_key projections (M=10); emits fp32 + planes ----
__global__ __launch_bounds__(256)
void gemm_small2(const float* __restrict__ A, const float* __restrict__ W,
                 const float* __restrict__ bias, float* __restrict__ Cf,
                 u16* __restrict__ Ch, u16* __restrict__ Cl, int K, int N)
{
    const int m = blockIdx.x, n = threadIdx.x;
    float acc = bias[n];
    for (int k = 0; k < K; ++k) acc += A[(size_t)m * K + k] * W[(size_t)k * N + n];
    Cf[(size_t)m * N + n] = acc;
    const u16 h = bf16_rne(acc);
    Ch[(size_t)m * N + n] = h;
    Cl[(size_t)m * N + n] = bf16_rne(acc - bf16_to_f(h));
}

// ---- MFMA Hopfield attention: QK^T (split) -> Michelot sparsemax (regs) -> P@V ----
// Block = (b, h, 64-row query chunk). Inputs are hi/lo planes; ho out (nb,8,L,32) planes.
template<int L, int S, int SHARED>
__global__ __launch_bounds__(256)
void attn_mfma(const u16* __restrict__ qh, const u16* __restrict__ ql,
               const u16* __restrict__ kh, const u16* __restrict__ kl,
               const u16* __restrict__ vh, const u16* __restrict__ vl,
               u16* __restrict__ oh, u16* __restrict__ ol)
{
    constexpr int S16 = (S + 15) & ~15;
    constexpr int S32 = (S + 31) & ~31;
    constexpr int NT = S16 / 16;
    constexpr int KC = S32 / 32;
    constexpr int LC = L / 64;
    constexpr int QB = 64 * 32;
    constexpr int KB = S16 * 32;
    constexpr int VB = 32 * S32;
    constexpr int PB = 64 * S32;
    __shared__ __align__(16) u16 smem[2 * QB + 2 * KB + 2 * VB + PB];
    u16* const Q0 = smem;            u16* const Q1 = smem + QB;
    u16* const K0 = smem + 2 * QB;   u16* const K1 = K0 + KB;
    u16* const V0 = K1 + KB;         u16* const V1 = V0 + VB;
    u16* const Ps = V1 + VB;
    float* const OutL = (float*)smem;   // [64][36], aliased over Q/K (dead post-QK)

    const int t = threadIdx.x;
    const int lc = (LC == 1) ? 0 : (blockIdx.x % LC);
    const int bh = (LC == 1) ? blockIdx.x : (blockIdx.x / LC);
    const int b = bh >> 3, h = bh & 7;
    const int qrow0 = lc * 64;

    // --- stage Q (64 rows) and K (S rows), zero VT pad if needed ---
    for (int c = t; c < 256; c += 256) {
        const int row = c >> 2, kc = c & 3;
        const size_t g = (size_t)(b * L + qrow0 + row) * 256 + h * 32 + kc * 8;
        *(uint4*)&Q0[row * 32 + kc * 8] = *(const uint4*)(qh + g);
        *(uint4*)&Q1[row * 32 + kc * 8] = *(const uint4*)(ql + g);
    }
    for (int c = t; c < S * 4; c += 256) {
        const int row = c >> 2, kc = c & 3;
        const size_t g = (size_t)(SHARED ? row : b * S + row) * 256 + h * 32 + kc * 8;
        *(uint4*)&K0[row * 32 + kc * 8] = *(const uint4*)(kh + g);
        *(uint4*)&K1[row * 32 + kc * 8] = *(const uint4*)(kl + g);
    }
    if (S32 != S) {
        for (int i = t; i < VB; i += 256) { V0[i] = 0; V1[i] = 0; }
    }
    __syncthreads();
    // --- V: rows -> Ptmp(=Ps) -> transposed VT[e][j], per plane ---
    const u16* vpl0 = vh; const u16* vpl1 = vl;
    #pragma unroll
    for (int p = 0; p < 2; ++p) {
        const u16* vp = p ? vpl1 : vpl0;
        u16* vt = p ? V1 : V0;
        for (int c = t; c < S * 4; c += 256) {
            const int row = c >> 2, kc = c & 3;
            const size_t g = (size_t)(SHARED ? row : b * S + row) * 256 + h * 32 + kc * 8;
            *(uint4*)&Ps[row * 32 + kc * 8] = *(const uint4*)(vp + g);
        }
        __syncthreads();
        for (int c = t; c < S * 4; c += 256) {
            const int j = c >> 2, eg = c & 3;
            __align__(16) u16 tmp[8];
            *(uint4*)tmp = *(const uint4*)&Ps[j * 32 + eg * 8];
            #pragma unroll
            for (int i = 0; i < 8; ++i) vt[(eg * 8 + i) * S32 + j] = tmp[i];
        }
        __syncthreads();
    }
    if (S16 != S32) {
        for (int i = t; i < PB; i += 256) Ps[i] = 0;
        __syncthreads();
    }

    const int w = t >> 6, lane = t & 63;
    const int lm = lane & 15, quad = lane >> 4, kq = quad << 3;
    const int wr0 = w * 16;   // this wave's 16 rows

    // --- QK^T: A=Q (m=query row), B=K (n=key j); split 3-term ---
    const s8v fq0 = *(const s8v*)&Q0[(wr0 + lm) * 32 + kq];
    const s8v fq1 = *(const s8v*)&Q1[(wr0 + lm) * 32 + kq];
    f4v zac[NT] = {};
    #pragma unroll
    for (int nt = 0; nt < NT; ++nt) {
        const s8v fk0 = *(const s8v*)&K0[(nt * 16 + lm) * 32 + kq];
        const s8v fk1 = *(const s8v*)&K1[(nt * 16 + lm) * 32 + kq];
        zac[nt] = MFMA16(fq1, fk0, zac[nt], 0, 0, 0);
        zac[nt] = MFMA16(fq0, fk1, zac[nt], 0, 0, 0);
        zac[nt] = MFMA16(fq0, fk0, zac[nt], 0, 0, 0);
    }
    __syncthreads();   // all waves done with Q/K (OutL alias + P writes follow)

    const float scale = 0.17677669529663687f;  // 1/sqrt(32)
    float z[NT][4];
    #pragma unroll
    for (int nt = 0; nt < NT; ++nt)
        #pragma unroll
        for (int r = 0; r < 4; ++r) {
            float zz = zac[nt][r] * scale;
            if (nt * 16 + lm >= S) zz = -3.0e38f;   // folds away when 16|S
            z[nt][r] = zz;
        }

    // --- Michelot sparsemax: rows live in quad groups (16 lanes x NT regs) ---
    float tau[4], kprev[4];
    #pragma unroll
    for (int r = 0; r < 4; ++r) { tau[r] = -3.0e38f; kprev[r] = -1.f; }
    for (int it = 0; it <= S; ++it) {
        bool anych = false;
        #pragma unroll
        for (int r = 0; r < 4; ++r) {
            float cnt = 0.f, sum = 0.f;
            #pragma unroll
            for (int nt = 0; nt < NT; ++nt) {
                const bool a = z[nt][r] > tau[r];
                cnt += a ? 1.f : 0.f;
                sum += a ? z[nt][r] : 0.f;
            }
            #pragma unroll
            for (int off = 1; off <= 8; off <<= 1) {
                cnt += __shfl_xor(cnt, off);
                sum += __shfl_xor(sum, off);
            }
            if (cnt != kprev[r]) anych = true;
            kprev[r] = cnt;
            tau[r] = (sum - 1.f) / cnt;
        }
        if (__ballot(anych) == 0ULL) break;
    }

    // --- P = max(z - tau, 0) -> LDS (A-operand layout), then P@V via MFMA ---
    #pragma unroll
    for (int nt = 0; nt < NT; ++nt)
        #pragma unroll
        for (int r = 0; r < 4; ++r) {
            const int row = wr0 + quad * 4 + r;
            Ps[row * S32 + nt * 16 + lm] = bf16_rne(fmaxf(z[nt][r] - tau[r], 0.f));
        }
    f4v oac[2] = {};
    #pragma unroll
    for (int kc = 0; kc < KC; ++kc) {
        const s8v fp = *(const s8v*)&Ps[(wr0 + lm) * S32 + kc * 32 + kq];
        #pragma unroll
        for (int et = 0; et < 2; ++et) {
            const s8v fv0 = *(const s8v*)&V0[(et * 16 + lm) * S32 + kc * 32 + kq];
            const s8v fv1 = *(const s8v*)&V1[(et * 16 + lm) * S32 + kc * 32 + kq];
            oac[et] = MFMA16(fp, fv0, oac[et], 0, 0, 0);
            oac[et] = MFMA16(fp, fv1, oac[et], 0, 0, 0);
        }
    }

    // --- epilogue: C-layout -> OutL -> coalesced hi/lo global stores ---
    #pragma unroll
    for (int et = 0; et < 2; ++et)
        #pragma unroll
        for (int r = 0; r < 4; ++r)
            OutL[(wr0 + quad * 4 + r) * 36 + et * 16 + lm] = oac[et][r];
    const int rrow = wr0 + (lane >> 2);
    const int e0 = (lane & 3) * 8;
    __align__(16) float f[8];
    *(float4*)&f[0] = *(const float4*)&OutL[rrow * 36 + e0];
    *(float4*)&f[4] = *(const float4*)&OutL[rrow * 36 + e0 + 4];
    __align__(16) u16 hh[8], ll[8];
    #pragma unroll
    for (int i = 0; i < 8; ++i) {
        hh[i] = bf16_rne(f[i]);
        ll[i] = bf16_rne(f[i] - bf16_to_f(hh[i]));
    }
    const size_t g = (((size_t)b * 8 + h) * L + qrow0 + rrow) * 32 + e0;
    *(uint4*)(oh + g) = *(const uint4*)hh;
    *(uint4*)(ol + g) = *(const uint4*)ll;
}

// ---- LayerNorm over last dim (256), split planes in/out ----
__global__ __launch_bounds__(256)
void layernorm_pl(const u16* __restrict__ xh, const u16* __restrict__ xl,
                  const float* __restrict__ g, const float* __restrict__ bb,
                  u16* __restrict__ oh, u16* __restrict__ ol)
{
    const int w = threadIdx.x >> 6, lane = threadIdx.x & 63;
    const size_t row = (size_t)blockIdx.x * 4 + w;
    const size_t base = row * 256 + lane * 4;
    const uint2 hv = *(const uint2*)&xh[base];
    const uint2 lv = *(const uint2*)&xl[base];
    float f[4];
    f[0] = bf16_to_f((u16)(hv.x & 0xFFFFu)) + bf16_to_f((u16)(lv.x & 0xFFFFu));
    f[1] = bf16_to_f((u16)(hv.x >> 16))     + bf16_to_f((u16)(lv.x >> 16));
    f[2] = bf16_to_f((u16)(hv.y & 0xFFFFu)) + bf16_to_f((u16)(lv.y & 0xFFFFu));
    f[3] = bf16_to_f((u16)(hv.y >> 16))     + bf16_to_f((u16)(lv.y >> 16));
    float s = f[0] + f[1] + f[2] + f[3];
    float sq = f[0]*f[0] + f[1]*f[1] + f[2]*f[2] + f[3]*f[3];
    #pragma unroll
    for (int off = 32; off >= 1; off >>= 1) {
        s  += __shfl_xor(s, off);
        sq += __shfl_xor(sq, off);
    }
    const float mean = s * (1.f / 256.f);
    const float var  = sq * (1.f / 256.f) - mean * mean;
    const float rstd = rsqrtf(var + 1e-5f);
    const float4 gv = *(const float4*)&g[lane * 4];
    const float4 bv = *(const float4*)&bb[lane * 4];
    const float gs[4] = {gv.x, gv.y, gv.z, gv.w};
    const float bs[4] = {bv.x, bv.y, bv.z, bv.w};
    u16 hh[4], ll[4];
    #pragma unroll
    for (int r = 0; r < 4; ++r) {
        const float o = (f[r] - mean) * rstd * gs[r] + bs[r];
        hh[r] = bf16_rne(o);
        ll[r] = bf16_rne(o - bf16_to_f(hh[r]));
    }
    uint2 hp, lp;
    hp.x = (u32)hh[0] | ((u32)hh[1] << 16); hp.y = (u32)hh[2] | ((u32)hh[3] << 16);
    lp.x = (u32)ll[0] | ((u32)ll[1] << 16); lp.y = (u32)ll[2] | ((u32)ll[3] << 16);
    *(uint2*)(oh + base) = hp;
    *(uint2*)(ol + base) = lp;
}

// ---- (B,d1,d2,256) -> (B,d2,d1,256) for one u16 plane, 8-elem granules ----
__global__ __launch_bounds__(256)
void transpose_pl(const uint4* __restrict__ in, uint4* __restrict__ out, int d1, int d2)
{
    const size_t idx = (size_t)blockIdx.x * 256 + threadIdx.x;
    const int c = (int)(idx & 31);
    const size_t r = idx >> 5;
    const int j = (int)(r % d2);
    const size_t r2 = r / d2;
    const int i = (int)(r2 % d1);
    const int bb = (int)(r2 / d1);
    out[(((size_t)bb * d2 + j) * d1 + i) * 32 + c] = in[idx];
}

// ---- final: FO (b,seg=128,ts=64,256) planes -> d_out fp32 (b,ts,seg,256) ----
__global__ __launch_bounds__(256)
void final_combine(const u16* __restrict__ fh, const u16* __restrict__ fl,
                   float* __restrict__ out)
{
    const size_t idx = (size_t)blockIdx.x * 256 + threadIdx.x;
    const int c = (int)(idx & 31);
    const size_t r = idx >> 5;
    const int tt = (int)(r % 64);
    const size_t r2 = r / 64;
    const int sg = (int)(r2 % 128);
    const int bb = (int)(r2 / 128);
    const size_t ibase = r * 256 + (size_t)c * 8;
    const uint4 hv = *(const uint4*)(fh + ibase);
    const uint4 lv = *(const uint4*)(fl + ibase);
    const u32 hw[4] = {hv.x, hv.y, hv.z, hv.w};
    const u32 lw[4] = {lv.x, lv.y, lv.z, lv.w};
    __align__(16) float f[8];
    #pragma unroll
    for (int i = 0; i < 4; ++i) {
        f[i * 2]     = bf16_to_f((u16)(hw[i] & 0xFFFFu)) + bf16_to_f((u16)(lw[i] & 0xFFFFu));
        f[i * 2 + 1] = bf16_to_f((u16)(hw[i] >> 16))     + bf16_to_f((u16)(lw[i] >> 16));
    }
    const size_t orow = ((size_t)bb * 64 + tt) * 128 + sg;
    *(float4*)&out[orow * 256 + c * 8]     = *(const float4*)&f[0];
    *(float4*)&out[orow * 256 + c * 8 + 4] = *(const float4*)&f[4];
}

extern "C" void kernel_launch(void* const* d_in, const int* in_sizes, int n_in,
                              void* d_out, int out_size, void* d_ws, size_t ws_size,
                              hipStream_t stream)
{
    const float* x      = (const float*)d_in[0];
    const float* ct_wq  = (const float*)d_in[1];  const float* ct_bq = (const float*)d_in[2];
    const float* ct_wk  = (const float*)d_in[3];  const float* ct_bk = (const float*)d_in[4];
    const float* ct_wv  = (const float*)d_in[5];  const float* ct_bv = (const float*)d_in[6];
    const float* ct_wo  = (const float*)d_in[7];  const float* ct_bo = (const float*)d_in[8];
    const float* cs_wq  = (const float*)d_in[9];  const float* cs_bq = (const float*)d_in[10];
    const float* cs_wk  = (const float*)d_in[11]; const float* cs_bk = (const float*)d_in[12];
    const float* cs_wv  = (const float*)d_in[13]; const float* cs_bv = (const float*)d_in[14];
    const float* cs_wo  = (const float*)d_in[15]; const float* cs_bo = (const float*)d_in[16];
    const float* hp_wq  = (const float*)d_in[17]; const float* hp_bq = (const float*)d_in[18];
    const float* hp_wk  = (const float*)d_in[19]; const float* hp_bk = (const float*)d_in[20];
    const float* hp_wv  = (const float*)d_in[21]; const float* hp_bv = (const float*)d_in[22];
    const float* hp_wo  = (const float*)d_in[23]; const float* hp_bo = (const float*)d_in[24];
    const float* cs_key = (const float*)d_in[25];
    const float* ln_g   = (const float*)d_in[26]; const float* ln_b   = (const float*)d_in[27];
    const float* m1_w1  = (const float*)d_in[28]; const float* m1_b1  = (const float*)d_in[29];
    const float* m1_w2  = (const float*)d_in[30]; const float* m1_b2  = (const float*)d_in[31];
    const float* m2_w1  = (const float*)d_in[32]; const float* m2_b1  = (const float*)d_in[33];
    const float* m2_w2  = (const float*)d_in[34]; const float* m2_b2  = (const float*)d_in[35];

    const size_t PS = 8388608ULL;          // u16 per plane (32768 x 256)
    u16* WS = (u16*)d_ws;
    auto SLOT = [&](int i) { return WS + (size_t)i * PS; };
    u16* WT = WS + 8 * PS;                 // split weights: 3,407,872 u16
    u16* SM = WT + 3407872;
    float* kp2f = (float*)SM;              // 2560 fp32
    float* v2f  = kp2f + 2560;
    u16* kp2h = (u16*)(v2f + 2560);
    u16* kp2l = kp2h + 2560;
    u16* v2h  = kp2l + 2560;
    u16* v2l  = v2h + 2560;
    u16* DQ3h = (u16*)d_out;               // d_out as scratch for q3 planes
    u16* DQ3l = DQ3h + PS;

    const dim3 blk(256);

    // ---- weight prep ----
    u16* w_h[14]; u16* w_l[14];
    {
        u16* wt = WT;
        const float* wsrc[14] = {ct_wq, ct_wk, ct_wv, ct_wo, cs_wq, cs_wo,
                                 hp_wq, hp_wk, hp_wv, hp_wo, m1_w1, m1_w2, m2_w1, m2_w2};
        const int wK[14] = {256,256,256,256,256,256,256,256,256,256,256,1024,256,1024};
        const int wN[14] = {256,256,256,256,256,256,256,256,256,256,1024,256,1024,256};
        for (int i = 0; i < 14; ++i) {
            w_h[i] = wt; w_l[i] = wt + (size_t)wK[i] * wN[i];
            wt += 2 * (size_t)wK[i] * wN[i];
            wconv<<<dim3(wN[i] / 32, wK[i] / 32), blk, 0, stream>>>(wsrc[i], w_h[i], w_l[i], wK[i], wN[i]);
        }
    }

    auto G = [&](const u16* Ah_, const u16* Al_, int wi, const float* bias_,
                 u16* Ch_, u16* Cl_, int m, int n, int kk,
                 int gelu, int resmode, const float* Rf_, const u16* Rh_, const u16* Rl_) {
        dim3 grd(n / 128, m / 128);
        if (gelu)
            gemm_mfma<1,0><<<grd, blk, 0, stream>>>(Ah_, Al_, w_h[wi], w_l[wi], bias_,
                                                    nullptr, nullptr, nullptr, Ch_, Cl_, m, n, kk);
        else if (resmode == 1)
            gemm_mfma<0,1><<<grd, blk, 0, stream>>>(Ah_, Al_, w_h[wi], w_l[wi], bias_,
                                                    Rf_, nullptr, nullptr, Ch_, Cl_, m, n, kk);
        else if (resmode == 2)
            gemm_mfma<0,2><<<grd, blk, 0, stream>>>(Ah_, Al_, w_h[wi], w_l[wi], bias_,
                                                    nullptr, Rh_, Rl_, Ch_, Cl_, m, n, kk);
        else
            gemm_mfma<0,0><<<grd, blk, 0, stream>>>(Ah_, Al_, w_h[wi], w_l[wi], bias_,
                                                    nullptr, nullptr, nullptr, Ch_, Cl_, m, n, kk);
    };

    const int M = 32768, Mc = 16384;
    const size_t CO = (size_t)Mc * 256;    // per-chunk plane offset (u16)

    // ---- x -> split planes ----
    split_f32<<<dim3(4096), blk, 0, stream>>>(x, SLOT(0), SLOT(1));

    // ---- ct Hopfield: S=128, L=128, nb=256 ----
    G(SLOT(0), SLOT(1), 0, ct_bq, SLOT(2), SLOT(3), M, 256, 256, 0, 0, nullptr, nullptr, nullptr); // q1
    G(SLOT(0), SLOT(1), 1, ct_bk, SLOT(4), SLOT(5), M, 256, 256, 0, 0, nullptr, nullptr, nullptr); // k1
    G(SLOT(4), SLOT(5), 2, ct_bv, SLOT(6), SLOT(7), M, 256, 256, 0, 0, nullptr, nullptr, nullptr); // v1=V(k1)
    attn_mfma<128,128,0><<<dim3(4096), blk, 0, stream>>>(SLOT(2), SLOT(3), SLOT(4), SLOT(5),
                                                         SLOT(6), SLOT(7), SLOT(0), SLOT(1));      // ho1
    G(SLOT(0), SLOT(1), 3, ct_bo, SLOT(2), SLOT(3), M, 256, 256, 0, 1, x, nullptr, nullptr);       // dim_in

    // ---- MLP1 (2 chunks; hidden planes span SLOT4..5 and SLOT6..7) ----
    for (int c = 0; c < 2; ++c) {
        const u16* dh = SLOT(2) + c * CO; const u16* dl = SLOT(3) + c * CO;
        G(dh, dl, 10, m1_b1, SLOT(4), SLOT(6), Mc, 1024, 256, 1, 0, nullptr, nullptr, nullptr);
        G(SLOT(4), SLOT(6), 11, m1_b2, SLOT(0) + c * CO, SLOT(1) + c * CO, Mc, 256, 1024,
          0, 2, nullptr, dh, dl);
    }

    // ---- (b,ts,seg,D) -> (b,seg,ts,D): series_in ----
    transpose_pl<<<dim3(4096), blk, 0, stream>>>((const uint4*)SLOT(0), (uint4*)SLOT(2), 64, 128);
    transpose_pl<<<dim3(4096), blk, 0, stream>>>((const uint4*)SLOT(1), (uint4*)SLOT(3), 64, 128);

    // ---- hp/cs projections from series_in ----
    G(SLOT(2), SLOT(3), 7, hp_bk, SLOT(0), SLOT(1), M, 256, 256, 0, 0, nullptr, nullptr, nullptr); // k3
    G(SLOT(0), SLOT(1), 8, hp_bv, SLOT(4), SLOT(5), M, 256, 256, 0, 0, nullptr, nullptr, nullptr); // v3
    G(SLOT(2), SLOT(3), 6, hp_bq, DQ3h, DQ3l,       M, 256, 256, 0, 0, nullptr, nullptr, nullptr); // q3
    G(SLOT(2), SLOT(3), 4, cs_bq, SLOT(6), SLOT(7), M, 256, 256, 0, 0, nullptr, nullptr, nullptr); // q2

    // ---- hp Hopfield: self, S=64, L=64, nb=512 ----
    attn_mfma<64,64,0><<<dim3(4096), blk, 0, stream>>>(DQ3h, DQ3l, SLOT(0), SLOT(1),
                                                       SLOT(4), SLOT(5), SLOT(2), SLOT(3));        // ho3
    G(SLOT(2), SLOT(3), 9, hp_bo, SLOT(0), SLOT(1), M, 256, 256, 0, 0, nullptr, nullptr, nullptr); // pooled

    // ---- cs Hopfield: shared K/V from cs_key, S=10 ----
    gemm_small2<<<dim3(10), blk, 0, stream>>>(cs_key, cs_wk, cs_bk, kp2f, kp2h, kp2l, 256, 256);
    gemm_small2<<<dim3(10), blk, 0, stream>>>(kp2f,   cs_wv, cs_bv, v2f,  v2h,  v2l,  256, 256);
    attn_mfma<64,10,1><<<dim3(4096), blk, 0, stream>>>(SLOT(6), SLOT(7), kp2h, kp2l,
                                                       v2h, v2l, SLOT(4), SLOT(5));                // ho2
    G(SLOT(4), SLOT(5), 5, cs_bo, SLOT(6), SLOT(7), M, 256, 256, 0, 2,
      nullptr, SLOT(0), SLOT(1));                                                                  // series_h + pooled

    // ---- LN + MLP2 ----
    layernorm_pl<<<dim3(8192), blk, 0, stream>>>(SLOT(6), SLOT(7), ln_g, ln_b, SLOT(2), SLOT(3));
    for (int c = 0; c < 2; ++c) {
        const u16* dh = SLOT(2) + c * CO; const u16* dl = SLOT(3) + c * CO;
        G(dh, dl, 12, m2_b1, SLOT(0), SLOT(4), Mc, 1024, 256, 1, 0, nullptr, nullptr, nullptr);
        G(SLOT(0), SLOT(4), 13, m2_b2, SLOT(6) + c * CO, SLOT(7) + c * CO, Mc, 256, 1024,
          0, 2, nullptr, dh, dl);
    }

    // ---- final transpose + combine -> d_out fp32 ----
    final_combine<<<dim3(4096), blk, 0, stream>>>(SLOT(6), SLOT(7), (float*)d_out);
}

// Round 5
// 882.640 us; speedup vs baseline: 3.8485x; 1.6136x over previous
//
#include <hip/hip_runtime.h>
#include <math.h>

// STHM layer. B=4, TS=64, SEG=128, D=256, H=8, dh=32, DFF=1024.
// Plain-bf16 MFMA GEMMs + attention (global_load_lds staging); residual streams fp32.

typedef unsigned short u16;
typedef unsigned int u32;
typedef __attribute__((ext_vector_type(8))) short s8v;   // 8 bf16 (4 VGPRs) MFMA frag
typedef __attribute__((ext_vector_type(4))) float f4v;   // MFMA accumulator

#define MFMA16 __builtin_amdgcn_mfma_f32_16x16x32_bf16

#define ASYNC16(lds, g) __builtin_amdgcn_global_load_lds( \
    (const __attribute__((address_space(1))) unsigned int*)(const void*)(g), \
    (__attribute__((address_space(3))) unsigned int*)(void*)(lds), 16, 0, 0)

__device__ __forceinline__ float gelu_exact(float x) {
    return 0.5f * x * (1.0f + erff(x * 0.70710678118654752f));
}
__device__ __forceinline__ u16 bf16_rne(float f) {
    u32 u = __float_as_uint(f);
    return (u16)((u + 0x7FFFu + ((u >> 16) & 1u)) >> 16);
}
__device__ __forceinline__ float bf16_to_f(u16 h) {
    return __uint_as_float((u32)h << 16);
}

// ---- Weight prep: W(K,N fp32) -> Wh (N,K bf16, transposed) ----
__global__ __launch_bounds__(256)
void wconv(const float* __restrict__ W, u16* __restrict__ Wh, int K, int N)
{
    __shared__ float tile[32][33];
    const int t = threadIdx.x;
    const int n0 = blockIdx.x * 32, k0 = blockIdx.y * 32;
    const int r = t >> 3, c = (t & 7) << 2;
    const float4 f = *(const float4*)&W[(size_t)(k0 + r) * N + n0 + c];
    tile[r][c] = f.x; tile[r][c + 1] = f.y; tile[r][c + 2] = f.z; tile[r][c + 3] = f.w;
    __syncthreads();
    u32 hp[2];
    #pragma unroll
    for (int p = 0; p < 2; ++p) {
        const u16 h0 = bf16_rne(tile[c + p * 2][r]);
        const u16 h1 = bf16_rne(tile[c + p * 2 + 1][r]);
        hp[p] = (u32)h0 | ((u32)h1 << 16);
    }
    uint2 hv; hv.x = hp[0]; hv.y = hp[1];
    *(uint2*)&Wh[(size_t)(n0 + r) * K + k0 + c] = hv;
}

// ---- fp32 -> bf16 plane (8 elems/thread) ----
__global__ __launch_bounds__(256)
void conv_hi(const float* __restrict__ x, u16* __restrict__ xh)
{
    const size_t base = ((size_t)blockIdx.x * 256 + threadIdx.x) * 8;
    const float4 a = *(const float4*)(x + base);
    const float4 b = *(const float4*)(x + base + 4);
    const float fs[8] = {a.x, a.y, a.z, a.w, b.x, b.y, b.z, b.w};
    __align__(16) u16 hh[8];
    #pragma unroll
    for (int i = 0; i < 8; ++i) hh[i] = bf16_rne(fs[i]);
    *(uint4*)(xh + base) = *(const uint4*)hh;
}

// ---- bias concat: bqk1=[ct_bq|ct_bk] (512), bqkq=[hp_bq|hp_bk|cs_bq] (768) ----
__global__ __launch_bounds__(256)
void bias_concat(const float* a0, const float* a1, float* o1,
                 const float* b0, const float* b1, const float* b2, float* o2)
{
    const int t = threadIdx.x;
    o1[t] = a0[t]; o1[256 + t] = a1[t];
    o2[t] = b0[t]; o2[256 + t] = b1[t]; o2[512 + t] = b2[t];
}

// ---- bf16 MFMA GEMM: C = A(M,K,lda) @ W(K,N) + bias [+Rf] [gelu] ----
// OUTMODE: 0 bf16 plane, 1 bf16+fp32, 2 fp32 only.
template<int GELU, int RES, int OUTMODE>
__global__ __launch_bounds__(256)
void gemm_bf16(const u16* __restrict__ A, int lda, const u16* __restrict__ W,
               const float* __restrict__ bias, const float* __restrict__ Rf,
               u16* __restrict__ Cb, float* __restrict__ Cf,
               int M, int N, int K)
{
    __shared__ __align__(16) u16 As[128 * 32];
    __shared__ __align__(16) u16 Ws[128 * 32];
    const int t = threadIdx.x;
    const int bn = blockIdx.x, bm = blockIdx.y;
    const int w = t >> 6, lane = t & 63;
    const int wy = w >> 1, wx = w & 1;
    const int lm = lane & 15, quad = lane >> 4, kq = quad << 3;
    const int srow = lane >> 2, scol = (lane & 3) << 3;  // 16 rows x 4 chunks per instr
    const u16* gA = A + (size_t)(bm * 128 + w * 32 + srow) * lda + scol;
    const u16* gW = W + (size_t)(bn * 128 + w * 32 + srow) * K + scol;
    u16* const lA0 = &As[(w * 32) * 32];
    u16* const lA1 = &As[(w * 32 + 16) * 32];
    u16* const lW0 = &Ws[(w * 32) * 32];
    u16* const lW1 = &Ws[(w * 32 + 16) * 32];
    f4v acc[4][4] = {};   // [ic: out-col tile][jr: act-row tile]
    for (int k0 = 0; k0 < K; k0 += 32) {
        ASYNC16(lA0, gA + k0);
        ASYNC16(lA1, gA + k0 + (size_t)16 * lda);
        ASYNC16(lW0, gW + k0);
        ASYNC16(lW1, gW + k0 + (size_t)16 * K);
        __syncthreads();
        s8v fw[4], fa[4];
        #pragma unroll
        for (int i = 0; i < 4; ++i) {
            fw[i] = *(const s8v*)&Ws[(wx * 64 + i * 16 + lm) * 32 + kq];
            fa[i] = *(const s8v*)&As[(wy * 64 + i * 16 + lm) * 32 + kq];
        }
        #pragma unroll
        for (int ic = 0; ic < 4; ++ic)
            #pragma unroll
            for (int jr = 0; jr < 4; ++jr)
                acc[ic][jr] = MFMA16(fw[ic], fa[jr], acc[ic][jr], 0, 0, 0);
        __syncthreads();
    }
    #pragma unroll
    for (int ic = 0; ic < 4; ++ic) {
        const int col0 = bn * 128 + wx * 64 + ic * 16 + (quad << 2);
        const float4 bv = *(const float4*)&bias[col0];
        #pragma unroll
        for (int jr = 0; jr < 4; ++jr) {
            const int row = bm * 128 + wy * 64 + jr * 16 + lm;
            const size_t o = (size_t)row * N + col0;
            float v[4] = {acc[ic][jr][0] + bv.x, acc[ic][jr][1] + bv.y,
                          acc[ic][jr][2] + bv.z, acc[ic][jr][3] + bv.w};
            if (RES) {
                const float4 rv = *(const float4*)(Rf + o);
                v[0] += rv.x; v[1] += rv.y; v[2] += rv.z; v[3] += rv.w;
            }
            if (GELU) {
                #pragma unroll
                for (int r = 0; r < 4; ++r) v[r] = gelu_exact(v[r]);
            }
            if (OUTMODE != 2) {
                uint2 hp;
                hp.x = (u32)bf16_rne(v[0]) | ((u32)bf16_rne(v[1]) << 16);
                hp.y = (u32)bf16_rne(v[2]) | ((u32)bf16_rne(v[3]) << 16);
                *(uint2*)(Cb + o) = hp;
            }
            if (OUTMODE >= 1) {
                float4 fv; fv.x = v[0]; fv.y = v[1]; fv.z = v[2]; fv.w = v[3];
                *(float4*)(Cf + o) = fv;
            }
        }
    }
}

// ---- Tiny exact fp32 GEMM (M=10) for cs_key projections; optional bf16 plane ----
__global__ __launch_bounds__(256)
void gemm_small(const float* __restrict__ A, const float* __restrict__ W,
                const float* __restrict__ bias, float* __restrict__ Cf,
                u16* __restrict__ Ch, int K, int N)
{
    const int m = blockIdx.x, n = threadIdx.x;
    float acc = bias[n];
    for (int k = 0; k < K; ++k) acc += A[(size_t)m * K + k] * W[(size_t)k * N + n];
    Cf[(size_t)m * N + n] = acc;
    if (Ch) Ch[(size_t)m * N + n] = bf16_rne(acc);
}

// ---- cs V^T builder: v2f (10,256) fp32 -> VT2 (8,32,32) bf16, j>=10 zero ----
__global__ __launch_bounds__(256)
void cs_vt(const float* __restrict__ v2f, u16* __restrict__ VT2)
{
    const int c = threadIdx.x;   // col = h*32+e
    for (int j = 0; j < 32; ++j)
        VT2[c * 32 + j] = (j < 10) ? bf16_rne(v2f[(size_t)j * 256 + c]) : (u16)0;
}

// ---- V (M,256) bf16 -> VT (nb,8,32,S) bf16; block per (nb_idx, h) ----
template<int S>
__global__ __launch_bounds__(256)
void transpose_vt(const u16* __restrict__ V, u16* __restrict__ VT)
{
    __shared__ __align__(16) u16 Vs[S * 40];
    const int t = threadIdx.x;
    const int nb = blockIdx.x >> 3, h = blockIdx.x & 7;
    for (int idx = t; idx < S * 4; idx += 256) {
        const int row = idx >> 2, ch = idx & 3;
        *(uint4*)&Vs[row * 40 + ch * 8] =
            *(const uint4*)&V[((size_t)nb * S + row) * 256 + h * 32 + ch * 8];
    }
    __syncthreads();
    for (int idx = t; idx < 32 * S / 8; idx += 256) {
        const int e = idx / (S / 8), seg = idx % (S / 8);
        const int j0 = seg * 8;
        __align__(16) u16 tmp[8];
        #pragma unroll
        for (int i = 0; i < 8; ++i) tmp[i] = Vs[(j0 + i) * 40 + e];
        *(uint4*)&VT[(((size_t)nb * 8 + h) * 32 + e) * S + j0] = *(const uint4*)tmp;
    }
}

// ---- bf16 MFMA attention: QK^T -> Michelot sparsemax (regs) -> P@V^T ----
// Block = (b, h, 64-row q chunk). One barrier total; P wave-private.
template<int L, int S, int SHARED>
__global__ __launch_bounds__(256)
void attn_bf16(const u16* __restrict__ q, int ldq, int qcol0,
               const u16* __restrict__ k, int ldk, int kcol0,
               const u16* __restrict__ VT, u16* __restrict__ ho)
{
    constexpr int S16 = (S + 15) & ~15;
    constexpr int S32 = (S + 31) & ~31;
    constexpr int NT = S16 / 16;
    constexpr int KC = S32 / 32;
    constexpr int LC = L / 64;
    constexpr int SP = S32 + 8;
    __shared__ __align__(16) u16 Qs[64 * 32];
    __shared__ __align__(16) u16 Ks[S16 * 32];
    __shared__ __align__(16) u16 Vs[32 * SP];
    __shared__ __align__(16) u16 Ps[64 * SP];
    const int t = threadIdx.x;
    const int lc = (LC == 1) ? 0 : (blockIdx.x & (LC - 1));
    const int bh = (LC == 1) ? blockIdx.x : (blockIdx.x >> 1);
    const int b = bh >> 3, h = bh & 7;
    const int qrow0 = lc * 64;
    const int w = t >> 6, lane = t & 63;
    const int lm = lane & 15, quad = lane >> 4, kq = quad << 3;

    // --- stage Q (64 rows) via global_load_lds; head offset h*32! ---
    {
        const int srow = lane >> 2, scol = (lane & 3) << 3;
        const u16* g = q + (size_t)(b * L + qrow0 + w * 16 + srow) * ldq
                         + qcol0 + h * 32 + scol;
        ASYNC16(&Qs[(w * 16) * 32], g);
    }
    // --- stage K (head offset h*32) ---
    if (SHARED) {   // S=10: scalar staging + zero pad
        for (int idx = t; idx < S16 * 4; idx += 256) {
            const int row = idx >> 2, ch = idx & 3;
            uint4 val = make_uint4(0, 0, 0, 0);
            if (row < S) val = *(const uint4*)&k[(size_t)row * ldk + kcol0 + h * 32 + ch * 8];
            *(uint4*)&Ks[row * 32 + ch * 8] = val;
        }
    } else {
        const int srow = lane >> 2, scol = (lane & 3) << 3;
        for (int c = w; c < S / 16; c += 4) {
            const u16* g = k + (size_t)(b * S + c * 16 + srow) * ldk
                             + kcol0 + h * 32 + scol;
            ASYNC16(&Ks[(c * 16) * 32], g);
        }
    }
    // --- stage V^T (padded rows) ---
    for (int idx = t; idx < 32 * S32 / 8; idx += 256) {
        const int e = idx / (S32 / 8), ch = idx % (S32 / 8);
        const size_t src = SHARED ? ((size_t)(h * 32 + e) * S32 + ch * 8)
                                  : ((((size_t)b * 8 + h) * 32 + e) * S32 + ch * 8);
        *(uint4*)&Vs[e * SP + ch * 8] = *(const uint4*)&VT[src];
    }
    __syncthreads();

    // --- QK^T: per wave 16 q-rows; D col=j_local, row=l_local ---
    const s8v fq = *(const s8v*)&Qs[(w * 16 + lm) * 32 + kq];
    f4v zac[NT];
    #pragma unroll
    for (int nt = 0; nt < NT; ++nt) {
        zac[nt] = f4v{0.f, 0.f, 0.f, 0.f};
        const s8v fk = *(const s8v*)&Ks[(nt * 16 + lm) * 32 + kq];
        zac[nt] = MFMA16(fq, fk, zac[nt], 0, 0, 0);
    }
    const float scale = 0.17677669529663687f;  // 1/sqrt(32)
    float z[NT][4];
    #pragma unroll
    for (int nt = 0; nt < NT; ++nt)
        #pragma unroll
        for (int r = 0; r < 4; ++r) {
            float zz = zac[nt][r] * scale;
            if ((S & 15) && nt * 16 + lm >= S) zz = -3.0e38f;
            z[nt][r] = zz;
        }

    // --- Michelot: tau = (sum_active - 1)/cnt, active = {z > tau} ---
    float tau[4], kprev[4];
    #pragma unroll
    for (int r = 0; r < 4; ++r) { tau[r] = -3.0e38f; kprev[r] = -1.f; }
    for (int it = 0; it <= S; ++it) {
        bool anych = false;
        #pragma unroll
        for (int r = 0; r < 4; ++r) {
            float cnt = 0.f, sum = 0.f;
            #pragma unroll
            for (int nt = 0; nt < NT; ++nt) {
                const bool a = z[nt][r] > tau[r];
                cnt += a ? 1.f : 0.f;
                sum += a ? z[nt][r] : 0.f;
            }
            #pragma unroll
            for (int off = 1; off <= 8; off <<= 1) {
                cnt += __shfl_xor(cnt, off);
                sum += __shfl_xor(sum, off);
            }
            if (cnt != kprev[r]) anych = true;
            kprev[r] = cnt;
            tau[r] = (sum - 1.f) / cnt;
        }
        if (__ballot(anych) == 0ULL) break;
    }

    // --- P (wave-private rows) -> PV, no barrier needed ---
    u16* const Pw = &Ps[(w * 16) * SP];
    #pragma unroll
    for (int nt = 0; nt < NT; ++nt)
        #pragma unroll
        for (int r = 0; r < 4; ++r)
            Pw[(quad * 4 + r) * SP + nt * 16 + lm] = bf16_rne(fmaxf(z[nt][r] - tau[r], 0.f));
    if (S16 != S32) {   // zero pad cols [S16,S32)
        #pragma unroll
        for (int r = 0; r < 4; ++r)
            Pw[(quad * 4 + r) * SP + S16 + lm] = 0;
    }
    f4v oac[2] = {};
    #pragma unroll
    for (int kc = 0; kc < KC; ++kc) {
        const s8v fp = *(const s8v*)&Pw[lm * SP + kc * 32 + kq];
        #pragma unroll
        for (int et = 0; et < 2; ++et) {
            const s8v fv = *(const s8v*)&Vs[(et * 16 + lm) * SP + kc * 32 + kq];
            oac[et] = MFMA16(fp, fv, oac[et], 0, 0, 0);
        }
    }
    // --- store: D col=e, row=l_local; (nb,8,L,32) bf16 ---
    #pragma unroll
    for (int et = 0; et < 2; ++et)
        #pragma unroll
        for (int r = 0; r < 4; ++r) {
            const int l = qrow0 + w * 16 + quad * 4 + r;
            ho[(((size_t)b * 8 + h) * L + l) * 32 + et * 16 + lm] = bf16_rne(oac[et][r]);
        }
}

// ---- LayerNorm (in-place fp32) + bf16 plane out ----
__global__ __launch_bounds__(256)
void layernorm_dual(float* __restrict__ x, const float* __restrict__ g,
                    const float* __restrict__ bb, u16* __restrict__ oh)
{
    const int w = threadIdx.x >> 6, lane = threadIdx.x & 63;
    const size_t base = ((size_t)blockIdx.x * 4 + w) * 256 + lane * 4;
    const float4 xv = *(const float4*)&x[base];
    float s  = xv.x + xv.y + xv.z + xv.w;
    float sq = xv.x * xv.x + xv.y * xv.y + xv.z * xv.z + xv.w * xv.w;
    #pragma unroll
    for (int off = 32; off >= 1; off >>= 1) {
        s  += __shfl_xor(s, off);
        sq += __shfl_xor(sq, off);
    }
    const float mean = s * (1.f / 256.f);
    const float var  = sq * (1.f / 256.f) - mean * mean;
    const float rstd = rsqrtf(var + 1e-5f);
    const float4 gv = *(const float4*)&g[lane * 4];
    const float4 bv = *(const float4*)&bb[lane * 4];
    float4 o;
    o.x = (xv.x - mean) * rstd * gv.x + bv.x;
    o.y = (xv.y - mean) * rstd * gv.y + bv.y;
    o.z = (xv.z - mean) * rstd * gv.z + bv.z;
    o.w = (xv.w - mean) * rstd * gv.w + bv.w;
    *(float4*)&x[base] = o;
    uint2 hp;
    hp.x = (u32)bf16_rne(o.x) | ((u32)bf16_rne(o.y) << 16);
    hp.y = (u32)bf16_rne(o.z) | ((u32)bf16_rne(o.w) << 16);
    *(uint2*)(oh + base) = hp;
}

// ---- (B,d1,d2,256) -> (B,d2,d1,256), u16 plane, 8-elem granules ----
__global__ __launch_bounds__(256)
void transpose_pl(const uint4* __restrict__ in, uint4* __restrict__ out, int d1, int d2)
{
    const size_t idx = (size_t)blockIdx.x * 256 + threadIdx.x;
    const int c = (int)(idx & 31);
    const size_t r = idx >> 5;
    const int j = (int)(r % d2);
    const size_t r2 = r / d2;
    const int i = (int)(r2 % d1);
    const int bb = (int)(r2 / d1);
    out[(((size_t)bb * d2 + j) * d1 + i) * 32 + c] = in[idx];
}

// ---- (B,d1,d2,256) -> (B,d2,d1,256), fp32, float4 granules ----
__global__ __launch_bounds__(256)
void transpose_bd(const float4* __restrict__ in, float4* __restrict__ out, int d1, int d2)
{
    const size_t idx = (size_t)blockIdx.x * 256 + threadIdx.x;
    const int c = (int)(idx & 63);
    const size_t r = idx >> 6;
    const int j = (int)(r % d2);
    const size_t r2 = r / d2;
    const int i = (int)(r2 % d1);
    const int bb = (int)(r2 / d1);
    out[(((size_t)bb * d2 + j) * d1 + i) * 64 + c] = in[idx];
}

extern "C" void kernel_launch(void* const* d_in, const int* in_sizes, int n_in,
                              void* d_out, int out_size, void* d_ws, size_t ws_size,
                              hipStream_t stream)
{
    const float* x      = (const float*)d_in[0];
    const float* ct_wq  = (const float*)d_in[1];  const float* ct_bq = (const float*)d_in[2];
    const float* ct_wk  = (const float*)d_in[3];  const float* ct_bk = (const float*)d_in[4];
    const float* ct_wv  = (const float*)d_in[5];  const float* ct_bv = (const float*)d_in[6];
    const float* ct_wo  = (const float*)d_in[7];  const float* ct_bo = (const float*)d_in[8];
    const float* cs_wq  = (const float*)d_in[9];  const float* cs_bq = (const float*)d_in[10];
    const float* cs_wk  = (const float*)d_in[11]; const float* cs_bk = (const float*)d_in[12];
    const float* cs_wv  = (const float*)d_in[13]; const float* cs_bv = (const float*)d_in[14];
    const float* cs_wo  = (const float*)d_in[15]; const float* cs_bo = (const float*)d_in[16];
    const float* hp_wq  = (const float*)d_in[17]; const float* hp_bq = (const float*)d_in[18];
    const float* hp_wk  = (const float*)d_in[19]; const float* hp_bk = (const float*)d_in[20];
    const float* hp_wv  = (const float*)d_in[21]; const float* hp_bv = (const float*)d_in[22];
    const float* hp_wo  = (const float*)d_in[23]; const float* hp_bo = (const float*)d_in[24];
    const float* cs_key = (const float*)d_in[25];
    const float* ln_g   = (const float*)d_in[26]; const float* ln_b   = (const float*)d_in[27];
    const float* m1_w1  = (const float*)d_in[28]; const float* m1_b1  = (const float*)d_in[29];
    const float* m1_w2  = (const float*)d_in[30]; const float* m1_b2  = (const float*)d_in[31];
    const float* m2_w1  = (const float*)d_in[32]; const float* m2_b1  = (const float*)d_in[33];
    const float* m2_w2  = (const float*)d_in[34]; const float* m2_b2  = (const float*)d_in[35];

    const size_t PS = 8388608ULL;  // u16 per plane (32768 x 256)
    u16* WS = (u16*)d_ws;
    auto SLOT = [&](int i) { return WS + (size_t)i * PS; };
    u16* WT = WS + 8 * PS;
    // weight regions (N,K) bf16, concatenations contiguous along N:
    u16* Wqk1 = WT;                       // 512*256
    u16* Wv1  = Wqk1 + 512 * 256;         // 256*256
    u16* Wo1  = Wv1  + 65536;
    u16* Wqkq = Wo1  + 65536;             // 768*256
    u16* Wv3  = Wqkq + 768 * 256;
    u16* Wo3  = Wv3  + 65536;
    u16* Wo2  = Wo3  + 65536;
    u16* Wm11 = Wo2  + 65536;             // 1024*256
    u16* Wm12 = Wm11 + 262144;            // 256*1024
    u16* Wm21 = Wm12 + 262144;
    u16* Wm22 = Wm21 + 262144;
    float* bqk1 = (float*)(Wm22 + 262144);      // 512
    float* bqkq = bqk1 + 512;                   // 768
    float* kp2f = bqkq + 768;                   // 2560
    float* v2f  = kp2f + 2560;                  // 2560
    u16* k2h  = (u16*)(v2f + 2560);             // 2560
    u16* VT2  = k2h + 2560;                     // 8192

    const dim3 blk(256);
    const int M = 32768;

    // ---- weight prep (all hi-only, transposed) ----
    wconv<<<dim3(8, 8), blk, 0, stream>>>(ct_wq, Wqk1, 256, 256);
    wconv<<<dim3(8, 8), blk, 0, stream>>>(ct_wk, Wqk1 + 256 * 256, 256, 256);
    wconv<<<dim3(8, 8), blk, 0, stream>>>(ct_wv, Wv1, 256, 256);
    wconv<<<dim3(8, 8), blk, 0, stream>>>(ct_wo, Wo1, 256, 256);
    wconv<<<dim3(8, 8), blk, 0, stream>>>(hp_wq, Wqkq, 256, 256);
    wconv<<<dim3(8, 8), blk, 0, stream>>>(hp_wk, Wqkq + 256 * 256, 256, 256);
    wconv<<<dim3(8, 8), blk, 0, stream>>>(cs_wq, Wqkq + 512 * 256, 256, 256);
    wconv<<<dim3(8, 8), blk, 0, stream>>>(hp_wv, Wv3, 256, 256);
    wconv<<<dim3(8, 8), blk, 0, stream>>>(hp_wo, Wo3, 256, 256);
    wconv<<<dim3(8, 8), blk, 0, stream>>>(cs_wo, Wo2, 256, 256);
    wconv<<<dim3(32, 8), blk, 0, stream>>>(m1_w1, Wm11, 256, 1024);
    wconv<<<dim3(8, 32), blk, 0, stream>>>(m1_w2, Wm12, 1024, 256);
    wconv<<<dim3(32, 8), blk, 0, stream>>>(m2_w1, Wm21, 256, 1024);
    wconv<<<dim3(8, 32), blk, 0, stream>>>(m2_w2, Wm22, 1024, 256);
    bias_concat<<<dim3(1), blk, 0, stream>>>(ct_bq, ct_bk, bqk1, hp_bq, hp_bk, cs_bq, bqkq);

    // Slot plan (plane lifetimes):
    // S0: xh | HO1 | H1.0 | QKQ.0 | H2.0       S1: QK1.0 | H1.1 | QKQ.1 | H2.1
    // S2: QK1.1 | H1.2 | QKQ.2 | H2.2          S3: V1 | H1.3 | V3 | HO3 | HO2 | H2.3
    // S4: VT1 | DIMINh | D2h | VT3 | SUMf.0    S5: DIMINf.0 | SER | SUMf.1
    // S6: DIMINf.1 | FIN.0                     S7: DEh | FIN.1
    u16* xh = SLOT(0);
    u16* QK1 = SLOT(1);
    u16* V1 = SLOT(3);
    u16* VT1 = SLOT(4);
    u16* HO1 = SLOT(0);
    float* DIMINf = (float*)SLOT(5);
    u16* DIMINh = SLOT(4);
    u16* H1 = SLOT(0);
    u16* D2h = SLOT(4);
    u16* SER = SLOT(5);
    u16* QKQ = SLOT(0);
    u16* V3 = SLOT(3);
    u16* VT3 = SLOT(4);
    u16* HO3 = SLOT(3);
    float* POOL = (float*)d_out;
    u16* HO2 = SLOT(3);
    float* SUMf = (float*)SLOT(4);
    u16* DEh = SLOT(7);
    u16* H2 = SLOT(0);
    float* FIN = (float*)SLOT(6);

    // ---- t1: x -> bf16 plane ----
    conv_hi<<<dim3(4096), blk, 0, stream>>>(x, xh);
    // ---- t2: fused q1|k1 ----
    gemm_bf16<0,0,0><<<dim3(4, 256), blk, 0, stream>>>(xh, 256, Wqk1, bqk1, nullptr,
                                                       QK1, nullptr, M, 512, 256);
    // ---- t3: v1 = V(k1) ----
    gemm_bf16<0,0,0><<<dim3(2, 256), blk, 0, stream>>>(QK1 + 256, 512, Wv1, ct_bv, nullptr,
                                                       V1, nullptr, M, 256, 256);
    // ---- t4: VT1 ----
    transpose_vt<128><<<dim3(2048), blk, 0, stream>>>(V1, VT1);
    // ---- t5: ct attention (S=128, L=128, nb=256) ----
    attn_bf16<128,128,0><<<dim3(4096), blk, 0, stream>>>(QK1, 512, 0, QK1, 512, 256, VT1, HO1);
    // ---- t6: dim_in = x + enc (dual out) ----
    gemm_bf16<0,1,1><<<dim3(2, 256), blk, 0, stream>>>(HO1, 256, Wo1, ct_bo, x,
                                                       DIMINh, DIMINf, M, 256, 256);
    // ---- t7: MLP1 fc1 (gelu) ----
    gemm_bf16<1,0,0><<<dim3(8, 256), blk, 0, stream>>>(DIMINh, 256, Wm11, m1_b1, nullptr,
                                                       H1, nullptr, M, 1024, 256);
    // ---- t8: MLP1 fc2 + residual ----
    gemm_bf16<0,1,0><<<dim3(2, 256), blk, 0, stream>>>(H1, 1024, Wm12, m1_b2, DIMINf,
                                                       D2h, nullptr, M, 256, 1024);
    // ---- t9: (b,ts,seg,D) -> (b,seg,ts,D) ----
    transpose_pl<<<dim3(4096), blk, 0, stream>>>((const uint4*)D2h, (uint4*)SER, 64, 128);
    // ---- t10: fused q3|k3|q2 ----
    gemm_bf16<0,0,0><<<dim3(6, 256), blk, 0, stream>>>(SER, 256, Wqkq, bqkq, nullptr,
                                                       QKQ, nullptr, M, 768, 256);
    // ---- t11: v3 = V(k3) ----
    gemm_bf16<0,0,0><<<dim3(2, 256), blk, 0, stream>>>(QKQ + 256, 768, Wv3, hp_bv, nullptr,
                                                       V3, nullptr, M, 256, 256);
    // ---- t12: VT3 ----
    transpose_vt<64><<<dim3(4096), blk, 0, stream>>>(V3, VT3);
    // ---- t13: hp attention (S=64, L=64, nb=512) ----
    attn_bf16<64,64,0><<<dim3(4096), blk, 0, stream>>>(QKQ, 768, 0, QKQ, 768, 256, VT3, HO3);
    // ---- t14: pooled_h (fp32, into d_out scratch) ----
    gemm_bf16<0,0,2><<<dim3(2, 256), blk, 0, stream>>>(HO3, 256, Wo3, hp_bo, nullptr,
                                                       nullptr, POOL, M, 256, 256);
    // ---- t15: cs tiny chain + attention (S=10 shared) ----
    gemm_small<<<dim3(10), blk, 0, stream>>>(cs_key, cs_wk, cs_bk, kp2f, k2h, 256, 256);
    gemm_small<<<dim3(10), blk, 0, stream>>>(kp2f, cs_wv, cs_bv, v2f, nullptr, 256, 256);
    cs_vt<<<dim3(1), blk, 0, stream>>>(v2f, VT2);
    attn_bf16<64,10,1><<<dim3(4096), blk, 0, stream>>>(QKQ, 768, 512, k2h, 256, 0, VT2, HO2);
    // ---- t16: sum = series_h + pooled (fp32) ----
    gemm_bf16<0,1,2><<<dim3(2, 256), blk, 0, stream>>>(HO2, 256, Wo2, cs_bo, POOL,
                                                       nullptr, SUMf, M, 256, 256);
    // ---- t17: LN (in-place) + bf16 plane ----
    layernorm_dual<<<dim3(8192), blk, 0, stream>>>(SUMf, ln_g, ln_b, DEh);
    // ---- t18: MLP2 fc1 (gelu) ----
    gemm_bf16<1,0,0><<<dim3(8, 256), blk, 0, stream>>>(DEh, 256, Wm21, m2_b1, nullptr,
                                                       H2, nullptr, M, 1024, 256);
    // ---- t19: MLP2 fc2 + residual (fp32) ----
    gemm_bf16<0,1,2><<<dim3(2, 256), blk, 0, stream>>>(H2, 1024, Wm22, m2_b2, SUMf,
                                                       nullptr, FIN, M, 256, 1024);
    // ---- t20: (b,seg,ts,D) -> (b,ts,seg,D) into d_out ----
    transpose_bd<<<dim3(8192), blk, 0, stream>>>((const float4*)FIN, (float4*)d_out, 128, 64);
}

// Round 6
// 708.949 us; speedup vs baseline: 4.7914x; 1.2450x over previous
//
#include <hip/hip_runtime.h>
#include <math.h>

// STHM layer. B=4, TS=64, SEG=128, D=256, H=8, dh=32, DFF=1024.
// Plain-bf16 MFMA GEMMs (BK=64, XOR-swizzled LDS) + single-barrier MFMA attention.
// Residual streams fp32. Tiny cs-projections K-parallel.

typedef unsigned short u16;
typedef unsigned int u32;
typedef __attribute__((ext_vector_type(8))) short s8v;   // 8 bf16 (4 VGPRs) MFMA frag
typedef __attribute__((ext_vector_type(4))) float f4v;   // MFMA accumulator

#define MFMA16 __builtin_amdgcn_mfma_f32_16x16x32_bf16

#define ASYNC16(lds, g) __builtin_amdgcn_global_load_lds( \
    (const __attribute__((address_space(1))) unsigned int*)(const void*)(g), \
    (__attribute__((address_space(3))) unsigned int*)(void*)(lds), 16, 0, 0)

__device__ __forceinline__ float gelu_exact(float x) {
    return 0.5f * x * (1.0f + erff(x * 0.70710678118654752f));
}
__device__ __forceinline__ u16 bf16_rne(float f) {
    u32 u = __float_as_uint(f);
    return (u16)((u + 0x7FFFu + ((u >> 16) & 1u)) >> 16);
}
__device__ __forceinline__ float bf16_to_f(u16 h) {
    return __uint_as_float((u32)h << 16);
}

// ---- Batched weight prep: W(K,N fp32) -> Wh (N,K bf16, transposed), 14 mats ----
struct WB {
    const float* src[14];
    u16* dst[14];
    int K[14], N[14];
};
__global__ __launch_bounds__(256)
void wconv_batch(WB wb)
{
    __shared__ float tile[32][33];
    const int mi = blockIdx.y;
    const int K = wb.K[mi], N = wb.N[mi];
    const int tilesN = N >> 5;
    if ((int)blockIdx.x >= tilesN * (K >> 5)) return;
    const int n0 = (blockIdx.x % tilesN) * 32, k0 = (blockIdx.x / tilesN) * 32;
    const float* W = wb.src[mi];
    u16* Wh = wb.dst[mi];
    const int t = threadIdx.x;
    const int r = t >> 3, c = (t & 7) << 2;
    const float4 f = *(const float4*)&W[(size_t)(k0 + r) * N + n0 + c];
    tile[r][c] = f.x; tile[r][c + 1] = f.y; tile[r][c + 2] = f.z; tile[r][c + 3] = f.w;
    __syncthreads();
    u32 hp[2];
    #pragma unroll
    for (int p = 0; p < 2; ++p) {
        const u16 h0 = bf16_rne(tile[c + p * 2][r]);
        const u16 h1 = bf16_rne(tile[c + p * 2 + 1][r]);
        hp[p] = (u32)h0 | ((u32)h1 << 16);
    }
    uint2 hv; hv.x = hp[0]; hv.y = hp[1];
    *(uint2*)&Wh[(size_t)(n0 + r) * K + k0 + c] = hv;
}

// ---- fp32 -> bf16 plane (8 elems/thread) ----
__global__ __launch_bounds__(256)
void conv_hi(const float* __restrict__ x, u16* __restrict__ xh)
{
    const size_t base = ((size_t)blockIdx.x * 256 + threadIdx.x) * 8;
    const float4 a = *(const float4*)(x + base);
    const float4 b = *(const float4*)(x + base + 4);
    const float fs[8] = {a.x, a.y, a.z, a.w, b.x, b.y, b.z, b.w};
    __align__(16) u16 hh[8];
    #pragma unroll
    for (int i = 0; i < 8; ++i) hh[i] = bf16_rne(fs[i]);
    *(uint4*)(xh + base) = *(const uint4*)hh;
}

// ---- bias concat ----
__global__ __launch_bounds__(256)
void bias_concat(const float* a0, const float* a1, float* o1,
                 const float* b0, const float* b1, const float* b2, float* o2)
{
    const int t = threadIdx.x;
    o1[t] = a0[t]; o1[256 + t] = a1[t];
    o2[t] = b0[t]; o2[256 + t] = b1[t]; o2[512 + t] = b2[t];
}

// ---- bf16 MFMA GEMM, BK=64, XOR-swizzled LDS rows (row stride 64 u16) ----
// chunk-of-16B at (row, c) stored at chunk position c ^ (row & 7).
// OUTMODE: 0 bf16 plane, 1 bf16+fp32, 2 fp32 only.
template<int GELU, int RES, int OUTMODE>
__global__ __launch_bounds__(256)
void gemm_bf16(const u16* __restrict__ A, int lda, const u16* __restrict__ W,
               const float* __restrict__ bias, const float* __restrict__ Rf,
               u16* __restrict__ Cb, float* __restrict__ Cf,
               int M, int N, int K)
{
    __shared__ __align__(16) u16 As[128 * 64];
    __shared__ __align__(16) u16 Ws[128 * 64];
    const int t = threadIdx.x;
    const int bn = blockIdx.x, bm = blockIdx.y;
    const int w = t >> 6, lane = t & 63;
    const int wy = w >> 1, wx = w & 1;
    const int lm = lane & 15, quad = lane >> 4, kq = quad << 3;
    const int srow = lane >> 3;                        // 0..7
    const int scol = (((lane & 7) ^ srow) << 3);       // swizzled source chunk (u16)
    const u16* gA = A + (size_t)(bm * 128 + w * 32 + srow) * lda + scol;
    const u16* gW = W + (size_t)(bn * 128 + w * 32 + srow) * K + scol;
    f4v acc[4][4] = {};   // [ic: out-col tile][jr: act-row tile]
    for (int k0 = 0; k0 < K; k0 += 64) {
        #pragma unroll
        for (int r8 = 0; r8 < 4; ++r8) {
            ASYNC16(&As[(w * 32 + r8 * 8) * 64], gA + k0 + (size_t)(r8 * 8) * lda);
            ASYNC16(&Ws[(w * 32 + r8 * 8) * 64], gW + k0 + (size_t)(r8 * 8) * K);
        }
        __syncthreads();
        #pragma unroll
        for (int ks = 0; ks < 2; ++ks) {
            const int ch = ks * 4 + quad;              // 16B chunk index 0..7
            const int sw = ((ch ^ (lm & 7)) << 3);     // swizzled read offset (u16)
            s8v fw[4], fa[4];
            #pragma unroll
            for (int i = 0; i < 4; ++i) {
                fw[i] = *(const s8v*)&Ws[(wx * 64 + i * 16 + lm) * 64 + sw];
                fa[i] = *(const s8v*)&As[(wy * 64 + i * 16 + lm) * 64 + sw];
            }
            #pragma unroll
            for (int ic = 0; ic < 4; ++ic)
                #pragma unroll
                for (int jr = 0; jr < 4; ++jr)
                    acc[ic][jr] = MFMA16(fw[ic], fa[jr], acc[ic][jr], 0, 0, 0);
        }
        __syncthreads();
    }
    #pragma unroll
    for (int ic = 0; ic < 4; ++ic) {
        const int col0 = bn * 128 + wx * 64 + ic * 16 + (quad << 2);
        const float4 bv = *(const float4*)&bias[col0];
        #pragma unroll
        for (int jr = 0; jr < 4; ++jr) {
            const int row = bm * 128 + wy * 64 + jr * 16 + lm;
            const size_t o = (size_t)row * N + col0;
            float v[4] = {acc[ic][jr][0] + bv.x, acc[ic][jr][1] + bv.y,
                          acc[ic][jr][2] + bv.z, acc[ic][jr][3] + bv.w};
            if (RES) {
                const float4 rv = *(const float4*)(Rf + o);
                v[0] += rv.x; v[1] += rv.y; v[2] += rv.z; v[3] += rv.w;
            }
            if (GELU) {
                #pragma unroll
                for (int r = 0; r < 4; ++r) v[r] = gelu_exact(v[r]);
            }
            if (OUTMODE != 2) {
                uint2 hp;
                hp.x = (u32)bf16_rne(v[0]) | ((u32)bf16_rne(v[1]) << 16);
                hp.y = (u32)bf16_rne(v[2]) | ((u32)bf16_rne(v[3]) << 16);
                *(uint2*)(Cb + o) = hp;
            }
            if (OUTMODE >= 1) {
                float4 fv; fv.x = v[0]; fv.y = v[1]; fv.z = v[2]; fv.w = v[3];
                *(float4*)(Cf + o) = fv;
            }
        }
    }
}

// ---- K-parallel tiny GEMM: C(10,N) = A(10,K) @ W(K,N) + bias ----
// grid (10, N/32); block = 32 n-lanes x 8 K-slices; coalesced W reads.
__global__ __launch_bounds__(256)
void gemm_tiny(const float* __restrict__ A, const float* __restrict__ W,
               const float* __restrict__ bias, float* __restrict__ Cf,
               u16* __restrict__ Ch, int K, int N)
{
    __shared__ float red[8][33];
    const int m = blockIdx.x;
    const int ncol = blockIdx.y * 32 + (threadIdx.x & 31);
    const int ks = threadIdx.x >> 5;
    const int kc = K >> 3;
    float p = 0.f;
    for (int k = ks * kc; k < (ks + 1) * kc; ++k)
        p = fmaf(A[(size_t)m * K + k], W[(size_t)k * N + ncol], p);
    red[ks][threadIdx.x & 31] = p;
    __syncthreads();
    if (ks == 0) {
        float s = bias[ncol];
        #pragma unroll
        for (int i = 0; i < 8; ++i) s += red[i][threadIdx.x & 31];
        Cf[(size_t)m * N + ncol] = s;
        if (Ch) Ch[(size_t)m * N + ncol] = bf16_rne(s);
    }
}

// ---- cs V^T builder: v2f (10,256) fp32 -> VT2 (8,32,32) bf16, j>=10 zero ----
__global__ __launch_bounds__(256)
void cs_vt(const float* __restrict__ v2f, u16* __restrict__ VT2)
{
    const int c = threadIdx.x;   // col = h*32+e
    for (int j = 0; j < 32; ++j)
        VT2[c * 32 + j] = (j < 10) ? bf16_rne(v2f[(size_t)j * 256 + c]) : (u16)0;
}

// ---- V (M,256) bf16 -> VT (nb,8,32,S) bf16; block per (nb_idx, h) ----
template<int S>
__global__ __launch_bounds__(256)
void transpose_vt(const u16* __restrict__ V, u16* __restrict__ VT)
{
    __shared__ __align__(16) u16 Vs[S * 40];
    const int t = threadIdx.x;
    const int nb = blockIdx.x >> 3, h = blockIdx.x & 7;
    for (int idx = t; idx < S * 4; idx += 256) {
        const int row = idx >> 2, ch = idx & 3;
        *(uint4*)&Vs[row * 40 + ch * 8] =
            *(const uint4*)&V[((size_t)nb * S + row) * 256 + h * 32 + ch * 8];
    }
    __syncthreads();
    for (int idx = t; idx < 32 * S / 8; idx += 256) {
        const int e = idx / (S / 8), seg = idx % (S / 8);
        const int j0 = seg * 8;
        __align__(16) u16 tmp[8];
        #pragma unroll
        for (int i = 0; i < 8; ++i) tmp[i] = Vs[(j0 + i) * 40 + e];
        *(uint4*)&VT[(((size_t)nb * 8 + h) * 32 + e) * S + j0] = *(const uint4*)tmp;
    }
}

// ---- bf16 MFMA attention: QK^T -> Michelot sparsemax (regs) -> P@V^T ----
// Block = (b, h, 64-row q chunk). One barrier total; P wave-private.
template<int L, int S, int SHARED>
__global__ __launch_bounds__(256)
void attn_bf16(const u16* __restrict__ q, int ldq, int qcol0,
               const u16* __restrict__ k, int ldk, int kcol0,
               const u16* __restrict__ VT, u16* __restrict__ ho)
{
    constexpr int S16 = (S + 15) & ~15;
    constexpr int S32 = (S + 31) & ~31;
    constexpr int NT = S16 / 16;
    constexpr int KC = S32 / 32;
    constexpr int LC = L / 64;
    constexpr int SP = S32 + 8;
    __shared__ __align__(16) u16 Qs[64 * 32];
    __shared__ __align__(16) u16 Ks[S16 * 32];
    __shared__ __align__(16) u16 Vs[32 * SP];
    __shared__ __align__(16) u16 Ps[64 * SP];
    const int t = threadIdx.x;
    const int lc = (LC == 1) ? 0 : (blockIdx.x & (LC - 1));
    const int bh = (LC == 1) ? blockIdx.x : (blockIdx.x >> 1);
    const int b = bh >> 3, h = bh & 7;
    const int qrow0 = lc * 64;
    const int w = t >> 6, lane = t & 63;
    const int lm = lane & 15, quad = lane >> 4, kq = quad << 3;

    // --- stage Q (64 rows) via global_load_lds; head offset h*32 ---
    {
        const int srow = lane >> 2, scol = (lane & 3) << 3;
        const u16* g = q + (size_t)(b * L + qrow0 + w * 16 + srow) * ldq
                         + qcol0 + h * 32 + scol;
        ASYNC16(&Qs[(w * 16) * 32], g);
    }
    // --- stage K (head offset h*32) ---
    if (SHARED) {   // S=10: scalar staging + zero pad
        for (int idx = t; idx < S16 * 4; idx += 256) {
            const int row = idx >> 2, ch = idx & 3;
            uint4 val = make_uint4(0, 0, 0, 0);
            if (row < S) val = *(const uint4*)&k[(size_t)row * ldk + kcol0 + h * 32 + ch * 8];
            *(uint4*)&Ks[row * 32 + ch * 8] = val;
        }
    } else {
        const int srow = lane >> 2, scol = (lane & 3) << 3;
        for (int c = w; c < S / 16; c += 4) {
            const u16* g = k + (size_t)(b * S + c * 16 + srow) * ldk
                             + kcol0 + h * 32 + scol;
            ASYNC16(&Ks[(c * 16) * 32], g);
        }
    }
    // --- stage V^T (padded rows) ---
    for (int idx = t; idx < 32 * S32 / 8; idx += 256) {
        const int e = idx / (S32 / 8), ch = idx % (S32 / 8);
        const size_t src = SHARED ? ((size_t)(h * 32 + e) * S32 + ch * 8)
                                  : ((((size_t)b * 8 + h) * 32 + e) * S32 + ch * 8);
        *(uint4*)&Vs[e * SP + ch * 8] = *(const uint4*)&VT[src];
    }
    __syncthreads();

    // --- QK^T: per wave 16 q-rows; D col=j_local, row=l_local ---
    const s8v fq = *(const s8v*)&Qs[(w * 16 + lm) * 32 + kq];
    f4v zac[NT];
    #pragma unroll
    for (int nt = 0; nt < NT; ++nt) {
        zac[nt] = f4v{0.f, 0.f, 0.f, 0.f};
        const s8v fk = *(const s8v*)&Ks[(nt * 16 + lm) * 32 + kq];
        zac[nt] = MFMA16(fq, fk, zac[nt], 0, 0, 0);
    }
    const float scale = 0.17677669529663687f;  // 1/sqrt(32)
    float z[NT][4];
    #pragma unroll
    for (int nt = 0; nt < NT; ++nt)
        #pragma unroll
        for (int r = 0; r < 4; ++r) {
            float zz = zac[nt][r] * scale;
            if ((S & 15) && nt * 16 + lm >= S) zz = -3.0e38f;
            z[nt][r] = zz;
        }

    // --- Michelot: tau = (sum_active - 1)/cnt, active = {z > tau} ---
    float tau[4], kprev[4];
    #pragma unroll
    for (int r = 0; r < 4; ++r) { tau[r] = -3.0e38f; kprev[r] = -1.f; }
    for (int it = 0; it <= S; ++it) {
        bool anych = false;
        #pragma unroll
        for (int r = 0; r < 4; ++r) {
            float cnt = 0.f, sum = 0.f;
            #pragma unroll
            for (int nt = 0; nt < NT; ++nt) {
                const bool a = z[nt][r] > tau[r];
                cnt += a ? 1.f : 0.f;
                sum += a ? z[nt][r] : 0.f;
            }
            #pragma unroll
            for (int off = 1; off <= 8; off <<= 1) {
                cnt += __shfl_xor(cnt, off);
                sum += __shfl_xor(sum, off);
            }
            if (cnt != kprev[r]) anych = true;
            kprev[r] = cnt;
            tau[r] = (sum - 1.f) / cnt;
        }
        if (__ballot(anych) == 0ULL) break;
    }

    // --- P (wave-private rows) -> PV, no barrier needed ---
    u16* const Pw = &Ps[(w * 16) * SP];
    #pragma unroll
    for (int nt = 0; nt < NT; ++nt)
        #pragma unroll
        for (int r = 0; r < 4; ++r)
            Pw[(quad * 4 + r) * SP + nt * 16 + lm] = bf16_rne(fmaxf(z[nt][r] - tau[r], 0.f));
    if (S16 != S32) {   // zero pad cols [S16,S32)
        #pragma unroll
        for (int r = 0; r < 4; ++r)
            Pw[(quad * 4 + r) * SP + S16 + lm] = 0;
    }
    f4v oac[2] = {};
    #pragma unroll
    for (int kc = 0; kc < KC; ++kc) {
        const s8v fp = *(const s8v*)&Pw[lm * SP + kc * 32 + kq];
        #pragma unroll
        for (int et = 0; et < 2; ++et) {
            const s8v fv = *(const s8v*)&Vs[(et * 16 + lm) * SP + kc * 32 + kq];
            oac[et] = MFMA16(fp, fv, oac[et], 0, 0, 0);
        }
    }
    // --- store: D col=e, row=l_local; (nb,8,L,32) bf16 ---
    #pragma unroll
    for (int et = 0; et < 2; ++et)
        #pragma unroll
        for (int r = 0; r < 4; ++r) {
            const int l = qrow0 + w * 16 + quad * 4 + r;
            ho[(((size_t)b * 8 + h) * L + l) * 32 + et * 16 + lm] = bf16_rne(oac[et][r]);
        }
}

// ---- LayerNorm (in-place fp32) + bf16 plane out ----
__global__ __launch_bounds__(256)
void layernorm_dual(float* __restrict__ x, const float* __restrict__ g,
                    const float* __restrict__ bb, u16* __restrict__ oh)
{
    const int w = threadIdx.x >> 6, lane = threadIdx.x & 63;
    const size_t base = ((size_t)blockIdx.x * 4 + w) * 256 + lane * 4;
    const float4 xv = *(const float4*)&x[base];
    float s  = xv.x + xv.y + xv.z + xv.w;
    float sq = xv.x * xv.x + xv.y * xv.y + xv.z * xv.z + xv.w * xv.w;
    #pragma unroll
    for (int off = 32; off >= 1; off >>= 1) {
        s  += __shfl_xor(s, off);
        sq += __shfl_xor(sq, off);
    }
    const float mean = s * (1.f / 256.f);
    const float var  = sq * (1.f / 256.f) - mean * mean;
    const float rstd = rsqrtf(var + 1e-5f);
    const float4 gv = *(const float4*)&g[lane * 4];
    const float4 bv = *(const float4*)&bb[lane * 4];
    float4 o;
    o.x = (xv.x - mean) * rstd * gv.x + bv.x;
    o.y = (xv.y - mean) * rstd * gv.y + bv.y;
    o.z = (xv.z - mean) * rstd * gv.z + bv.z;
    o.w = (xv.w - mean) * rstd * gv.w + bv.w;
    *(float4*)&x[base] = o;
    uint2 hp;
    hp.x = (u32)bf16_rne(o.x) | ((u32)bf16_rne(o.y) << 16);
    hp.y = (u32)bf16_rne(o.z) | ((u32)bf16_rne(o.w) << 16);
    *(uint2*)(oh + base) = hp;
}

// ---- (B,d1,d2,256) -> (B,d2,d1,256), u16 plane, 8-elem granules ----
__global__ __launch_bounds__(256)
void transpose_pl(const uint4* __restrict__ in, uint4* __restrict__ out, int d1, int d2)
{
    const size_t idx = (size_t)blockIdx.x * 256 + threadIdx.x;
    const int c = (int)(idx & 31);
    const size_t r = idx >> 5;
    const int j = (int)(r % d2);
    const size_t r2 = r / d2;
    const int i = (int)(r2 % d1);
    const int bb = (int)(r2 / d1);
    out[(((size_t)bb * d2 + j) * d1 + i) * 32 + c] = in[idx];
}

// ---- (B,d1,d2,256) -> (B,d2,d1,256), fp32, float4 granules ----
__global__ __launch_bounds__(256)
void transpose_bd(const float4* __restrict__ in, float4* __restrict__ out, int d1, int d2)
{
    const size_t idx = (size_t)blockIdx.x * 256 + threadIdx.x;
    const int c = (int)(idx & 63);
    const size_t r = idx >> 6;
    const int j = (int)(r % d2);
    const size_t r2 = r / d2;
    const int i = (int)(r2 % d1);
    const int bb = (int)(r2 / d1);
    out[(((size_t)bb * d2 + j) * d1 + i) * 64 + c] = in[idx];
}

extern "C" void kernel_launch(void* const* d_in, const int* in_sizes, int n_in,
                              void* d_out, int out_size, void* d_ws, size_t ws_size,
                              hipStream_t stream)
{
    const float* x      = (const float*)d_in[0];
    const float* ct_wq  = (const float*)d_in[1];  const float* ct_bq = (const float*)d_in[2];
    const float* ct_wk  = (const float*)d_in[3];  const float* ct_bk = (const float*)d_in[4];
    const float* ct_wv  = (const float*)d_in[5];  const float* ct_bv = (const float*)d_in[6];
    const float* ct_wo  = (const float*)d_in[7];  const float* ct_bo = (const float*)d_in[8];
    const float* cs_wq  = (const float*)d_in[9];  const float* cs_bq = (const float*)d_in[10];
    const float* cs_wk  = (const float*)d_in[11]; const float* cs_bk = (const float*)d_in[12];
    const float* cs_wv  = (const float*)d_in[13]; const float* cs_bv = (const float*)d_in[14];
    const float* cs_wo  = (const float*)d_in[15]; const float* cs_bo = (const float*)d_in[16];
    const float* hp_wq  = (const float*)d_in[17]; const float* hp_bq = (const float*)d_in[18];
    const float* hp_wk  = (const float*)d_in[19]; const float* hp_bk = (const float*)d_in[20];
    const float* hp_wv  = (const float*)d_in[21]; const float* hp_bv = (const float*)d_in[22];
    const float* hp_wo  = (const float*)d_in[23]; const float* hp_bo = (const float*)d_in[24];
    const float* cs_key = (const float*)d_in[25];
    const float* ln_g   = (const float*)d_in[26]; const float* ln_b   = (const float*)d_in[27];
    const float* m1_w1  = (const float*)d_in[28]; const float* m1_b1  = (const float*)d_in[29];
    const float* m1_w2  = (const float*)d_in[30]; const float* m1_b2  = (const float*)d_in[31];
    const float* m2_w1  = (const float*)d_in[32]; const float* m2_b1  = (const float*)d_in[33];
    const float* m2_w2  = (const float*)d_in[34]; const float* m2_b2  = (const float*)d_in[35];

    const size_t PS = 8388608ULL;  // u16 per plane (32768 x 256)
    u16* WS = (u16*)d_ws;
    auto SLOT = [&](int i) { return WS + (size_t)i * PS; };
    u16* WT = WS + 8 * PS;
    // weight regions (N,K) bf16, concatenations contiguous along N:
    u16* Wqk1 = WT;                       // 512*256
    u16* Wv1  = Wqk1 + 512 * 256;         // 256*256
    u16* Wo1  = Wv1  + 65536;
    u16* Wqkq = Wo1  + 65536;             // 768*256
    u16* Wv3  = Wqkq + 768 * 256;
    u16* Wo3  = Wv3  + 65536;
    u16* Wo2  = Wo3  + 65536;
    u16* Wm11 = Wo2  + 65536;             // 1024*256
    u16* Wm12 = Wm11 + 262144;            // 256*1024
    u16* Wm21 = Wm12 + 262144;
    u16* Wm22 = Wm21 + 262144;
    float* bqk1 = (float*)(Wm22 + 262144);      // 512
    float* bqkq = bqk1 + 512;                   // 768
    float* kp2f = bqkq + 768;                   // 2560
    float* v2f  = kp2f + 2560;                  // 2560
    u16* k2h  = (u16*)(v2f + 2560);             // 2560
    u16* VT2  = k2h + 2560;                     // 8192

    const dim3 blk(256);
    const int M = 32768;

    // ---- batched weight prep (1 launch) + bias concat ----
    {
        WB wb;
        const float* s14[14] = {ct_wq, ct_wk, ct_wv, ct_wo, hp_wq, hp_wk, cs_wq,
                                hp_wv, hp_wo, cs_wo, m1_w1, m1_w2, m2_w1, m2_w2};
        u16* d14[14] = {Wqk1, Wqk1 + 65536, Wv1, Wo1, Wqkq, Wqkq + 65536, Wqkq + 131072,
                        Wv3, Wo3, Wo2, Wm11, Wm12, Wm21, Wm22};
        for (int i = 0; i < 14; ++i) {
            wb.src[i] = s14[i]; wb.dst[i] = d14[i];
            wb.K[i] = (i == 11 || i == 13) ? 1024 : 256;
            wb.N[i] = (i == 10 || i == 12) ? 1024 : 256;
        }
        wconv_batch<<<dim3(256, 14), blk, 0, stream>>>(wb);
        bias_concat<<<dim3(1), blk, 0, stream>>>(ct_bq, ct_bk, bqk1, hp_bq, hp_bk, cs_bq, bqkq);
    }

    // Slot plan (plane lifetimes):
    // S0: xh | HO1 | H1.0 | QKQ.0 | H2.0       S1: QK1.0 | H1.1 | QKQ.1 | H2.1
    // S2: QK1.1 | H1.2 | QKQ.2 | H2.2          S3: V1 | H1.3 | V3 | HO3 | HO2 | H2.3
    // S4: VT1 | DIMINh | D2h | VT3 | SUMf.0    S5: DIMINf.0 | SER | SUMf.1
    // S6: DIMINf.1 | FIN.0                     S7: DEh | FIN.1
    u16* xh = SLOT(0);
    u16* QK1 = SLOT(1);
    u16* V1 = SLOT(3);
    u16* VT1 = SLOT(4);
    u16* HO1 = SLOT(0);
    float* DIMINf = (float*)SLOT(5);
    u16* DIMINh = SLOT(4);
    u16* H1 = SLOT(0);
    u16* D2h = SLOT(4);
    u16* SER = SLOT(5);
    u16* QKQ = SLOT(0);
    u16* V3 = SLOT(3);
    u16* VT3 = SLOT(4);
    u16* HO3 = SLOT(3);
    float* POOL = (float*)d_out;
    u16* HO2 = SLOT(3);
    float* SUMf = (float*)SLOT(4);
    u16* DEh = SLOT(7);
    u16* H2 = SLOT(0);
    float* FIN = (float*)SLOT(6);

    // ---- t1: x -> bf16 plane ----
    conv_hi<<<dim3(4096), blk, 0, stream>>>(x, xh);
    // ---- t2: fused q1|k1 ----
    gemm_bf16<0,0,0><<<dim3(4, 256), blk, 0, stream>>>(xh, 256, Wqk1, bqk1, nullptr,
                                                       QK1, nullptr, M, 512, 256);
    // ---- t3: v1 = V(k1) ----
    gemm_bf16<0,0,0><<<dim3(2, 256), blk, 0, stream>>>(QK1 + 256, 512, Wv1, ct_bv, nullptr,
                                                       V1, nullptr, M, 256, 256);
    // ---- t4: VT1 ----
    transpose_vt<128><<<dim3(2048), blk, 0, stream>>>(V1, VT1);
    // ---- t5: ct attention (S=128, L=128, nb=256) ----
    attn_bf16<128,128,0><<<dim3(4096), blk, 0, stream>>>(QK1, 512, 0, QK1, 512, 256, VT1, HO1);
    // ---- t6: dim_in = x + enc (dual out) ----
    gemm_bf16<0,1,1><<<dim3(2, 256), blk, 0, stream>>>(HO1, 256, Wo1, ct_bo, x,
                                                       DIMINh, DIMINf, M, 256, 256);
    // ---- t7: MLP1 fc1 (gelu) ----
    gemm_bf16<1,0,0><<<dim3(8, 256), blk, 0, stream>>>(DIMINh, 256, Wm11, m1_b1, nullptr,
                                                       H1, nullptr, M, 1024, 256);
    // ---- t8: MLP1 fc2 + residual ----
    gemm_bf16<0,1,0><<<dim3(2, 256), blk, 0, stream>>>(H1, 1024, Wm12, m1_b2, DIMINf,
                                                       D2h, nullptr, M, 256, 1024);
    // ---- t9: (b,ts,seg,D) -> (b,seg,ts,D) ----
    transpose_pl<<<dim3(4096), blk, 0, stream>>>((const uint4*)D2h, (uint4*)SER, 64, 128);
    // ---- t10: fused q3|k3|q2 ----
    gemm_bf16<0,0,0><<<dim3(6, 256), blk, 0, stream>>>(SER, 256, Wqkq, bqkq, nullptr,
                                                       QKQ, nullptr, M, 768, 256);
    // ---- t11: v3 = V(k3) ----
    gemm_bf16<0,0,0><<<dim3(2, 256), blk, 0, stream>>>(QKQ + 256, 768, Wv3, hp_bv, nullptr,
                                                       V3, nullptr, M, 256, 256);
    // ---- t12: VT3 ----
    transpose_vt<64><<<dim3(4096), blk, 0, stream>>>(V3, VT3);
    // ---- t13: hp attention (S=64, L=64, nb=512) ----
    attn_bf16<64,64,0><<<dim3(4096), blk, 0, stream>>>(QKQ, 768, 0, QKQ, 768, 256, VT3, HO3);
    // ---- t14: pooled_h (fp32, into d_out scratch) ----
    gemm_bf16<0,0,2><<<dim3(2, 256), blk, 0, stream>>>(HO3, 256, Wo3, hp_bo, nullptr,
                                                       nullptr, POOL, M, 256, 256);
    // ---- t15: cs tiny chain + attention (S=10 shared) ----
    gemm_tiny<<<dim3(10, 8), blk, 0, stream>>>(cs_key, cs_wk, cs_bk, kp2f, k2h, 256, 256);
    gemm_tiny<<<dim3(10, 8), blk, 0, stream>>>(kp2f, cs_wv, cs_bv, v2f, nullptr, 256, 256);
    cs_vt<<<dim3(1), blk, 0, stream>>>(v2f, VT2);
    attn_bf16<64,10,1><<<dim3(4096), blk, 0, stream>>>(QKQ, 768, 512, k2h, 256, 0, VT2, HO2);
    // ---- t16: sum = series_h + pooled (fp32) ----
    gemm_bf16<0,1,2><<<dim3(2, 256), blk, 0, stream>>>(HO2, 256, Wo2, cs_bo, POOL,
                                                       nullptr, SUMf, M, 256, 256);
    // ---- t17: LN (in-place) + bf16 plane ----
    layernorm_dual<<<dim3(8192), blk, 0, stream>>>(SUMf, ln_g, ln_b, DEh);
    // ---- t18: MLP2 fc1 (gelu) ----
    gemm_bf16<1,0,0><<<dim3(8, 256), blk, 0, stream>>>(DEh, 256, Wm21, m2_b1, nullptr,
                                                       H2, nullptr, M, 1024, 256);
    // ---- t19: MLP2 fc2 + residual (fp32) ----
    gemm_bf16<0,1,2><<<dim3(2, 256), blk, 0, stream>>>(H2, 1024, Wm22, m2_b2, SUMf,
                                                       nullptr, FIN, M, 256, 1024);
    // ---- t20: (b,seg,ts,D) -> (b,ts,seg,D) into d_out ----
    transpose_bd<<<dim3(8192), blk, 0, stream>>>((const float4*)FIN, (float4*)d_out, 128, 64);
}